// Round 3
// baseline (492.907 us; speedup 1.0000x reference)
//
#include <hip/hip_runtime.h>
#include <math.h>

// GraphDiffusionBlock: GAT(4 heads x 64ch) + time-proj + LayerNorm + SiLU
// Pipeline: detect idx dtype -> GEMM h=xW^T -> att logits -> time proj ->
//           CSR-by-dst build (hist/scan/scatter, int32 atomics only) ->
//           fused aggregate+epilogue (register accumulation, NO f32 atomics).
// Softmax is computed without max-shift (shift-invariant; logits ~N(0,1.3),
// |logit| <~ 7 => exp safe in f32).

#define LN_EPS 1e-5f
#define NEG_SLOPE 0.2f

// ---------------------------------------------------------------- dtype detect
// Reference says int64 but harness may deliver int32 (JAX x64 off). If the
// buffer really is int64, the first 64 int64 reads are all valid node ids in
// [0,N). If int32, an int64 read combines two int32 ids -> >= 2^32 unless the
// high word is 0 (prob ~(2e-5)^64 over 64 reads -> never).
__global__ void k_detect(const void* __restrict__ idx, long long n64, long long maxval,
                         int* __restrict__ flag) {
  if (blockIdx.x == 0 && threadIdx.x == 0) {
    const long long* p = (const long long*)idx;
    int cnt = (int)(n64 < 64 ? n64 : 64);
    int is64 = 1;
    for (int i = 0; i < cnt; ++i) {
      long long v = p[i];
      if (v < 0 || v >= maxval) { is64 = 0; break; }
    }
    *flag = is64;
  }
}

__device__ __forceinline__ long long load_idx(const void* p, long long i, int is64) {
  return is64 ? ((const long long*)p)[i] : (long long)((const int*)p)[i];
}

// ---------------------------------------------------------------- GEMM h = x @ W^T
// x:[N,128] W:[256,128] -> h:[N,256]. f32 vector ALU (no fp32 MFMA on CDNA4).
// Block: 256 thr, 64-node tile in LDS. Thread (nb=tid>>6, o=tid&63) computes
// channels {o, o+64, o+128, o+192} (one per head) for 16 nodes.
// Inner k-iter: 4 global float4 (W rows, L2-hot) + 16 LDS float4 (wave-broadcast)
// per 256 FMAs -> FMA-bound.
__global__ __launch_bounds__(256) void k_gemm(const float* __restrict__ x,
                                              const float* __restrict__ W,
                                              float* __restrict__ h, int N) {
  __shared__ float xs[64][128];
  int n0 = blockIdx.x * 64;
  int tid = threadIdx.x;
  for (int i = tid; i < 64 * 32; i += 256) {   // 2048 float4 loads
    int n = i >> 5;
    int k4 = i & 31;
    float4 v = make_float4(0.f, 0.f, 0.f, 0.f);
    if (n0 + n < N) v = reinterpret_cast<const float4*>(x)[(long long)(n0 + n) * 32 + k4];
    reinterpret_cast<float4*>(&xs[n][0])[k4] = v;
  }
  __syncthreads();

  int o  = tid & 63;
  int nb = tid >> 6;   // wave id -> nodes [nb*16, nb*16+16)
  int nbase = nb * 16;
  const float* w0 = W + (long long)o * 128;
  const float* w1 = W + (long long)(o + 64) * 128;
  const float* w2 = W + (long long)(o + 128) * 128;
  const float* w3 = W + (long long)(o + 192) * 128;

  float acc[16][4];
#pragma unroll
  for (int i = 0; i < 16; ++i)
#pragma unroll
    for (int j = 0; j < 4; ++j) acc[i][j] = 0.f;

  for (int k = 0; k < 128; k += 4) {
    float4 wv0 = *(const float4*)(w0 + k);
    float4 wv1 = *(const float4*)(w1 + k);
    float4 wv2 = *(const float4*)(w2 + k);
    float4 wv3 = *(const float4*)(w3 + k);
#pragma unroll
    for (int i = 0; i < 16; ++i) {
      float4 xv = *(const float4*)(&xs[nbase + i][k]);
      acc[i][0] += xv.x * wv0.x + xv.y * wv0.y + xv.z * wv0.z + xv.w * wv0.w;
      acc[i][1] += xv.x * wv1.x + xv.y * wv1.y + xv.z * wv1.z + xv.w * wv1.w;
      acc[i][2] += xv.x * wv2.x + xv.y * wv2.y + xv.z * wv2.z + xv.w * wv2.w;
      acc[i][3] += xv.x * wv3.x + xv.y * wv3.y + xv.z * wv3.z + xv.w * wv3.w;
    }
  }
#pragma unroll
  for (int i = 0; i < 16; ++i) {
    int n = n0 + nbase + i;
    if (n < N) {
      float* hp = h + (long long)n * 256 + o;
      hp[0] = acc[i][0]; hp[64] = acc[i][1]; hp[128] = acc[i][2]; hp[192] = acc[i][3];
    }
  }
}

// ---------------------------------------------------------------- attention logits
// a_s[n,hh] = sum_c h[n,hh,c]*att_src[hh,c]; wave per node, shfl reduce.
__global__ __launch_bounds__(256) void k_att(const float* __restrict__ h,
                                             const float* __restrict__ att_src,
                                             const float* __restrict__ att_dst,
                                             float* __restrict__ a_s, float* __restrict__ a_d,
                                             int N) {
  int wave = threadIdx.x >> 6;
  int lane = threadIdx.x & 63;
  int n = blockIdx.x * 4 + wave;
  if (n >= N) return;
  const float* hp = h + (long long)n * 256;
#pragma unroll
  for (int hh = 0; hh < 4; ++hh) {
    float v  = hp[hh * 64 + lane];
    float vs = v * att_src[hh * 64 + lane];
    float vd = v * att_dst[hh * 64 + lane];
#pragma unroll
    for (int m = 32; m; m >>= 1) {
      vs += __shfl_xor(vs, m, 64);
      vd += __shfl_xor(vd, m, 64);
    }
    if (lane == 0) { a_s[(long long)n * 4 + hh] = vs; a_d[(long long)n * 4 + hh] = vd; }
  }
}

// ---------------------------------------------------------------- time projection
// tp[b,c] = silu(time_emb[b,:]) @ tp_w[c,:] + tp_b[c]   (16x64 outputs, trivial)
__global__ void k_tp(const float* __restrict__ time_emb, const float* __restrict__ tp_w,
                     const float* __restrict__ tp_b, float* __restrict__ tp, int B) {
  int tid = blockIdx.x * blockDim.x + threadIdx.x;
  if (tid >= B * 64) return;
  int b = tid >> 6, c = tid & 63;
  const float* te = time_emb + (long long)b * 128;
  const float* wr = tp_w + (long long)c * 128;
  float s = 0.f;
  for (int k = 0; k < 128; ++k) {
    float t = te[k];
    s += (t / (1.f + expf(-t))) * wr[k];
  }
  tp[tid] = s + tp_b[c];
}

// ---------------------------------------------------------------- CSR build: hist
// cnt[dst]++ over E real edges + N self-loops (PyG GATConv adds self-loops).
__global__ __launch_bounds__(256) void k_hist(const void* __restrict__ ei,
                                              const int* __restrict__ flag,
                                              int* __restrict__ cnt,
                                              long long E, long long N) {
  long long Etot = E + N;
  int is64 = *flag;
  for (long long e = blockIdx.x * (long long)blockDim.x + threadIdx.x; e < Etot;
       e += (long long)gridDim.x * blockDim.x) {
    long long dst = (e < E) ? load_idx(ei, E + e, is64) : (e - E);
    atomicAdd(cnt + dst, 1);
  }
}

// ---------------------------------------------------------------- CSR build: scan
// Single block, 1024 thr (16 waves). Exclusive scan of cnt[N] -> rowptr[N+1],
// and a second copy into cursor[N] for the scatter pass.
// Per chunk: wave shfl-scan (no syncs) + 16-entry LDS scan by wave 0.
__global__ __launch_bounds__(1024) void k_scan(const int* __restrict__ cnt,
                                               int* __restrict__ rowptr,
                                               int* __restrict__ cursor, int N) {
  __shared__ int wsum[16];
  __shared__ int carry_sm;
  int tid = threadIdx.x, lane = tid & 63, w = tid >> 6;
  if (tid == 0) carry_sm = 0;
  __syncthreads();
  int nchunk = (N + 1023) / 1024;
  for (int c = 0; c < nchunk; ++c) {
    int i = c * 1024 + tid;
    int v = (i < N) ? cnt[i] : 0;
    // wave-inclusive scan
    int s = v;
#pragma unroll
    for (int off = 1; off < 64; off <<= 1) {
      int t = __shfl_up(s, off, 64);
      if (lane >= off) s += t;
    }
    if (lane == 63) wsum[w] = s;
    __syncthreads();
    // wave 0: inclusive scan of the 16 wave totals
    if (w == 0) {
      int t = (lane < 16) ? wsum[lane] : 0;
#pragma unroll
      for (int off = 1; off < 16; off <<= 1) {
        int u = __shfl_up(t, off, 64);
        if (lane >= off) t += u;
      }
      if (lane < 16) wsum[lane] = t;   // inclusive
    }
    __syncthreads();
    int woff = (w == 0) ? 0 : wsum[w - 1];
    int excl = carry_sm + woff + s - v;
    if (i < N) { rowptr[i] = excl; cursor[i] = excl; }
    __syncthreads();                       // all reads of carry_sm/wsum done
    if (tid == 0) carry_sm += wsum[15];    // chunk total
    __syncthreads();
  }
  if (threadIdx.x == 0) rowptr[N] = carry_sm;
}

// ---------------------------------------------------------------- CSR build: scatter
// col[pos] = src for each edge, pos = cursor[dst]++ (int atomics, L2-resident).
__global__ __launch_bounds__(256) void k_scatter(const void* __restrict__ ei,
                                                 const int* __restrict__ flag,
                                                 int* __restrict__ cursor,
                                                 int* __restrict__ col,
                                                 long long E, long long N) {
  long long Etot = E + N;
  int is64 = *flag;
  for (long long e = blockIdx.x * (long long)blockDim.x + threadIdx.x; e < Etot;
       e += (long long)gridDim.x * blockDim.x) {
    long long src, dst;
    if (e < E) { src = load_idx(ei, e, is64); dst = load_idx(ei, E + e, is64); }
    else       { src = dst = e - E; }
    int pos = atomicAdd(cursor + dst, 1);
    col[pos] = (int)src;
  }
}

// ---------------------------------------------------------------- fused aggregate + epilogue
// Wave per dst node. For each in-edge: sv_h = exp(leaky(a_s[src]+a_d[dst])),
// register-accumulate per-head numerators (lane=channel) and denominators.
// Then: out = mean_h(num_h/den_h) + bias + tp[batch]; LayerNorm(64); SiLU.
// No f32 atomics anywhere; h rows gathered coalesced (1KB/edge, L3-resident).
__global__ __launch_bounds__(256) void k_agg_csr(const int* __restrict__ rowptr,
                                                 const int* __restrict__ col,
                                                 const float* __restrict__ a_s,
                                                 const float* __restrict__ a_d,
                                                 const float* __restrict__ h,
                                                 const float* __restrict__ conv_bias,
                                                 const float* __restrict__ tpo,
                                                 const void* __restrict__ batch,
                                                 const int* __restrict__ flag,
                                                 const float* __restrict__ ln_g,
                                                 const float* __restrict__ ln_b,
                                                 float* __restrict__ out, long long N) {
  int wave = threadIdx.x >> 6, lane = threadIdx.x & 63;
  long long n = blockIdx.x * 4LL + wave;
  if (n >= N) return;
  float4 ad4 = *(const float4*)(a_d + n * 4);
  int beg = rowptr[n], end = rowptr[n + 1];   // end > beg (self-loop guaranteed)
  float d0 = 0.f, d1 = 0.f, d2 = 0.f, d3 = 0.f;
  float n0 = 0.f, n1 = 0.f, n2 = 0.f, n3 = 0.f;
  int src_next = col[beg];
  for (int e = beg; e < end; ++e) {
    int src = src_next;
    src_next = (e + 1 < end) ? col[e + 1] : 0;   // hide col load latency
    float4 as4 = *(const float4*)(a_s + (long long)src * 4);
    const float* hp = h + (long long)src * 256 + lane;
    float h0 = hp[0], h1 = hp[64], h2 = hp[128], h3 = hp[192];
    float l0 = as4.x + ad4.x; l0 = l0 > 0.f ? l0 : NEG_SLOPE * l0;
    float l1 = as4.y + ad4.y; l1 = l1 > 0.f ? l1 : NEG_SLOPE * l1;
    float l2 = as4.z + ad4.z; l2 = l2 > 0.f ? l2 : NEG_SLOPE * l2;
    float l3 = as4.w + ad4.w; l3 = l3 > 0.f ? l3 : NEG_SLOPE * l3;
    float s0 = expf(l0), s1 = expf(l1), s2 = expf(l2), s3 = expf(l3);
    d0 += s0; d1 += s1; d2 += s2; d3 += s3;
    n0 += s0 * h0; n1 += s1 * h1; n2 += s2 * h2; n3 += s3 * h3;
  }
  float v = 0.25f * (n0 / (d0 + 1e-16f) + n1 / (d1 + 1e-16f) +
                     n2 / (d2 + 1e-16f) + n3 / (d3 + 1e-16f));
  int is64 = *flag;
  long long b = load_idx(batch, n, is64);
  v += conv_bias[lane] + tpo[b * 64 + lane];
  float t1 = v, t2 = v * v;
#pragma unroll
  for (int m = 32; m; m >>= 1) {
    t1 += __shfl_xor(t1, m, 64);
    t2 += __shfl_xor(t2, m, 64);
  }
  float mean = t1 * (1.f / 64.f);
  float var  = t2 * (1.f / 64.f) - mean * mean;
  float y = (v - mean) * rsqrtf(var + LN_EPS) * ln_g[lane] + ln_b[lane];
  out[n * 64 + lane] = y / (1.f + expf(-y));
}

// ----------------------------------------------------------------------------
extern "C" void kernel_launch(void* const* d_in, const int* in_sizes, int n_in,
                              void* d_out, int out_size, void* d_ws, size_t ws_size,
                              hipStream_t stream) {
  const float* x        = (const float*)d_in[0];
  const void*  ei       = d_in[1];
  const float* time_emb = (const float*)d_in[2];
  const void*  batch    = d_in[3];
  const float* W        = (const float*)d_in[4];
  const float* att_src  = (const float*)d_in[5];
  const float* att_dst  = (const float*)d_in[6];
  const float* conv_b   = (const float*)d_in[7];
  const float* tp_w     = (const float*)d_in[8];
  const float* tp_b     = (const float*)d_in[9];
  const float* ln_g     = (const float*)d_in[10];
  const float* ln_b     = (const float*)d_in[11];

  long long N = in_sizes[0] / 128;   // 50000
  long long E = in_sizes[1] / 2;     // 800000
  long long B = in_sizes[2] / 128;   // 16
  long long Etot = E + N;

  // workspace layout (256B-aligned chunks), ~57 MB total
  char* p = (char*)d_ws;
  int*   flag   = (int*)p;   p += 256;
  float* h      = (float*)p; p += (size_t)N * 256 * 4;        // 51.2 MB
  float* a_s    = (float*)p; p += (size_t)N * 4 * 4;          // 800 KB
  float* a_d    = (float*)p; p += (size_t)N * 4 * 4;          // 800 KB
  int*   cnt    = (int*)p;   p += (size_t)N * 4;              // 200 KB
  int*   rowptr = (int*)p;   p += (size_t)(N + 1) * 4 + 252;  // 200 KB (keep align)
  int*   cursor = (int*)p;   p += (size_t)N * 4;              // 200 KB
  int*   col    = (int*)p;   p += (size_t)Etot * 4;           // 3.4 MB
  float* tpo    = (float*)p; p += (size_t)B * 64 * 4;         // 4 KB

  hipMemsetAsync(cnt, 0, (size_t)N * 4, stream);

  k_detect<<<1, 1, 0, stream>>>(ei, E, N, flag);
  k_gemm<<<dim3((unsigned)((N + 63) / 64)), 256, 0, stream>>>(x, W, h, (int)N);
  k_att<<<dim3((unsigned)((N + 3) / 4)), 256, 0, stream>>>(h, att_src, att_dst, a_s, a_d, (int)N);
  k_tp<<<dim3((unsigned)((B * 64 + 255) / 256)), 256, 0, stream>>>(time_emb, tp_w, tp_b, tpo, (int)B);
  k_hist<<<dim3(2048), 256, 0, stream>>>(ei, flag, cnt, E, N);
  k_scan<<<dim3(1), 1024, 0, stream>>>(cnt, rowptr, cursor, (int)N);
  k_scatter<<<dim3(2048), 256, 0, stream>>>(ei, flag, cursor, col, E, N);
  k_agg_csr<<<dim3((unsigned)((N + 3) / 4)), 256, 0, stream>>>(rowptr, col, a_s, a_d, h,
                                                               conv_b, tpo, batch, flag,
                                                               ln_g, ln_b, (float*)d_out, N);
}

// Round 5
// 456.116 us; speedup vs baseline: 1.0807x; 1.0807x over previous
//
#include <hip/hip_runtime.h>
#include <math.h>

// GraphDiffusionBlock: GAT(4 heads x 64ch) + time-proj + LayerNorm + SiLU
// Pipeline: detect idx dtype -> GEMM h=xW^T (+fused att logits) -> time proj ->
//           CSR-by-dst build (hist/scan/scatter, int32 atomics only) ->
//           fused aggregate+epilogue (register accumulation, NO f32 atomics).
// Softmax without max-shift (shift-invariant; logits ~N(0,1.3), max ~6 -> exp safe).

#define LN_EPS 1e-5f
#define NEG_SLOPE 0.2f

// ---------------------------------------------------------------- dtype detect
// Reference says int64 but harness may deliver int32 (JAX x64 off). If truly
// int64, the first 64 int64 reads are all valid ids in [0,N). If int32, an
// int64 read combines two ids -> >= 2^32 (prob of false-64 ~ (2e-5)^64 -> 0).
// 64 lanes load in parallel (was: 1 thread x 64 serial HBM loads ~ 25us).
__global__ void k_detect(const void* __restrict__ idx, long long n64, long long maxval,
                         int* __restrict__ flag) {
  int lane = threadIdx.x;
  long long cnt = n64 < 64 ? n64 : 64;
  int bad = 0;
  if (lane < cnt) {
    long long v = ((const long long*)idx)[lane];
    bad = (v < 0 || v >= maxval) ? 1 : 0;
  }
  unsigned long long m = __ballot(bad);
  if (lane == 0) *flag = (m == 0ULL) ? 1 : 0;
}

__device__ __forceinline__ long long load_idx(const void* p, long long i, int is64) {
  return is64 ? ((const long long*)p)[i] : (long long)((const int*)p)[i];
}

// ---------------------------------------------------------------- GEMM h = x @ W^T  (+ att logits)
// x:[N,128] W:[256,128] -> h:[N,256]; also a_s/a_d[n,hh] from acc registers
// (saves the 51MB h re-read of a separate kernel). Thread (nb=tid>>6, o=tid&63)
// holds channels {o, o+64, o+128, o+192} = one channel per head for 16 nodes,
// so a_s[n,hh] = wave-reduce(acc[i][hh] * att_src[hh*64+lane]).
__global__ __launch_bounds__(256) void k_gemm(const float* __restrict__ x,
                                              const float* __restrict__ W,
                                              const float* __restrict__ att_src,
                                              const float* __restrict__ att_dst,
                                              float* __restrict__ h,
                                              float* __restrict__ a_s,
                                              float* __restrict__ a_d, int N) {
  __shared__ float xs[64][128];
  int n0 = blockIdx.x * 64;
  int tid = threadIdx.x;
  for (int i = tid; i < 64 * 32; i += 256) {   // 2048 float4 loads
    int n = i >> 5;
    int k4 = i & 31;
    float4 v = make_float4(0.f, 0.f, 0.f, 0.f);
    if (n0 + n < N) v = reinterpret_cast<const float4*>(x)[(long long)(n0 + n) * 32 + k4];
    reinterpret_cast<float4*>(&xs[n][0])[k4] = v;
  }
  __syncthreads();

  int o  = tid & 63;
  int nb = tid >> 6;   // wave id -> nodes [nb*16, nb*16+16)
  int nbase = nb * 16;
  const float* w0 = W + (long long)o * 128;
  const float* w1 = W + (long long)(o + 64) * 128;
  const float* w2 = W + (long long)(o + 128) * 128;
  const float* w3 = W + (long long)(o + 192) * 128;

  float acc[16][4];
#pragma unroll
  for (int i = 0; i < 16; ++i)
#pragma unroll
    for (int j = 0; j < 4; ++j) acc[i][j] = 0.f;

  for (int k = 0; k < 128; k += 4) {
    float4 wv0 = *(const float4*)(w0 + k);
    float4 wv1 = *(const float4*)(w1 + k);
    float4 wv2 = *(const float4*)(w2 + k);
    float4 wv3 = *(const float4*)(w3 + k);
#pragma unroll
    for (int i = 0; i < 16; ++i) {
      float4 xv = *(const float4*)(&xs[nbase + i][k]);
      acc[i][0] += xv.x * wv0.x + xv.y * wv0.y + xv.z * wv0.z + xv.w * wv0.w;
      acc[i][1] += xv.x * wv1.x + xv.y * wv1.y + xv.z * wv1.z + xv.w * wv1.w;
      acc[i][2] += xv.x * wv2.x + xv.y * wv2.y + xv.z * wv2.z + xv.w * wv2.w;
      acc[i][3] += xv.x * wv3.x + xv.y * wv3.y + xv.z * wv3.z + xv.w * wv3.w;
    }
  }

  // att vectors for this thread's channel (lane = channel within head)
  float asv[4], adv[4];
#pragma unroll
  for (int hh = 0; hh < 4; ++hh) {
    asv[hh] = att_src[hh * 64 + o];
    adv[hh] = att_dst[hh * 64 + o];
  }

#pragma unroll
  for (int i = 0; i < 16; ++i) {
    int n = n0 + nbase + i;
    if (n < N) {
      float* hp = h + (long long)n * 256 + o;
      hp[0] = acc[i][0]; hp[64] = acc[i][1]; hp[128] = acc[i][2]; hp[192] = acc[i][3];
    }
    // fused attention logits: 8 simultaneous 64-lane butterfly reductions
    float r[8];
#pragma unroll
    for (int hh = 0; hh < 4; ++hh) {
      r[hh]     = acc[i][hh] * asv[hh];
      r[4 + hh] = acc[i][hh] * adv[hh];
    }
#pragma unroll
    for (int m = 32; m; m >>= 1)
#pragma unroll
      for (int j = 0; j < 8; ++j) r[j] += __shfl_xor(r[j], m, 64);
    if (o < 4 && n < N) {          // lanes 0..3 write head o
      a_s[(long long)n * 4 + o] = r[o];
      a_d[(long long)n * 4 + o] = r[4 + o];
    }
  }
}

// ---------------------------------------------------------------- time projection
__global__ void k_tp(const float* __restrict__ time_emb, const float* __restrict__ tp_w,
                     const float* __restrict__ tp_b, float* __restrict__ tp, int B) {
  int tid = blockIdx.x * blockDim.x + threadIdx.x;
  if (tid >= B * 64) return;
  int b = tid >> 6, c = tid & 63;
  const float* te = time_emb + (long long)b * 128;
  const float* wr = tp_w + (long long)c * 128;
  float s = 0.f;
  for (int k = 0; k < 128; ++k) {
    float t = te[k];
    s += (t / (1.f + __expf(-t))) * wr[k];
  }
  tp[tid] = s + tp_b[c];
}

// ---------------------------------------------------------------- CSR build: hist
__global__ __launch_bounds__(256) void k_hist(const void* __restrict__ ei,
                                              const int* __restrict__ flag,
                                              int* __restrict__ cnt,
                                              long long E, long long N) {
  long long Etot = E + N;
  int is64 = *flag;
  for (long long e = blockIdx.x * (long long)blockDim.x + threadIdx.x; e < Etot;
       e += (long long)gridDim.x * blockDim.x) {
    long long dst = (e < E) ? load_idx(ei, E + e, is64) : (e - E);
    atomicAdd(cnt + dst, 1);
  }
}

// ---------------------------------------------------------------- CSR build: scan
// Single block, 1024 thr, 4 elems/thread (int4). cnt is zero-padded to SC
// (multiple of 4096) so no tail guards; rowptr/cursor padded too.
__global__ __launch_bounds__(1024) void k_scan(const int* __restrict__ cnt,
                                               int* __restrict__ rowptr,
                                               int* __restrict__ cursor, int N, int SC) {
  __shared__ int wsum[16];
  __shared__ int carry_sm;
  int tid = threadIdx.x, lane = tid & 63, w = tid >> 6;
  if (tid == 0) carry_sm = 0;
  __syncthreads();
  int nchunk = SC / 4096;
  for (int c = 0; c < nchunk; ++c) {
    int base = c * 4096 + tid * 4;
    int4 v = *(const int4*)(cnt + base);
    int t0 = v.x, t1 = t0 + v.y, t2 = t1 + v.z, t3 = t2 + v.w;
    int s = t3;                                   // thread total
#pragma unroll
    for (int off = 1; off < 64; off <<= 1) {      // wave inclusive scan
      int t = __shfl_up(s, off, 64);
      if (lane >= off) s += t;
    }
    if (lane == 63) wsum[w] = s;
    __syncthreads();
    if (w == 0) {                                 // scan the 16 wave totals
      int t = (lane < 16) ? wsum[lane] : 0;
#pragma unroll
      for (int off = 1; off < 16; off <<= 1) {
        int u = __shfl_up(t, off, 64);
        if (lane >= off) t += u;
      }
      if (lane < 16) wsum[lane] = t;
    }
    __syncthreads();
    int woff = (w == 0) ? 0 : wsum[w - 1];
    int e0 = carry_sm + woff + (s - t3);          // exclusive prefix of v.x
    int4 ov = make_int4(e0, e0 + t0, e0 + t1, e0 + t2);
    *(int4*)(rowptr + base) = ov;
    *(int4*)(cursor + base) = ov;
    __syncthreads();
    if (tid == 0) carry_sm += wsum[15];
    __syncthreads();
  }
  if (tid == 0) rowptr[N] = carry_sm;
}

// ---------------------------------------------------------------- CSR build: scatter
__global__ __launch_bounds__(256) void k_scatter(const void* __restrict__ ei,
                                                 const int* __restrict__ flag,
                                                 int* __restrict__ cursor,
                                                 int* __restrict__ col,
                                                 long long E, long long N) {
  long long Etot = E + N;
  int is64 = *flag;
  for (long long e = blockIdx.x * (long long)blockDim.x + threadIdx.x; e < Etot;
       e += (long long)gridDim.x * blockDim.x) {
    long long src, dst;
    if (e < E) { src = load_idx(ei, e, is64); dst = load_idx(ei, E + e, is64); }
    else       { src = dst = e - E; }
    int pos = atomicAdd(cursor + dst, 1);
    col[pos] = (int)src;
  }
}

// ---------------------------------------------------------------- fused aggregate + epilogue
// Grid-stride wave per dst node (smooths Poisson-degree imbalance; 8192 waves
// = 32/CU of TLP for gather latency at 24 VGPR). Fast exp (__expf -> v_exp),
// fmax leaky-relu, fma accumulation; h rows gathered coalesced (4x256B, L3-hot).
__global__ __launch_bounds__(256) void k_agg_csr(const int* __restrict__ rowptr,
                                                 const int* __restrict__ col,
                                                 const float* __restrict__ a_s,
                                                 const float* __restrict__ a_d,
                                                 const float* __restrict__ h,
                                                 const float* __restrict__ conv_bias,
                                                 const float* __restrict__ tpo,
                                                 const void* __restrict__ batch,
                                                 const int* __restrict__ flag,
                                                 const float* __restrict__ ln_g,
                                                 const float* __restrict__ ln_b,
                                                 float* __restrict__ out, long long N) {
  int lane = threadIdx.x & 63;
  int is64 = *flag;
  long long wid = ((long long)blockIdx.x * blockDim.x + threadIdx.x) >> 6;
  long long nw  = ((long long)gridDim.x * blockDim.x) >> 6;
  float cb = conv_bias[lane];
  float gg = ln_g[lane], bb = ln_b[lane];
  const float* hl = h + lane;

  for (long long n = wid; n < N; n += nw) {
    float4 ad4 = *(const float4*)(a_d + n * 4);
    int beg = rowptr[n], end = rowptr[n + 1];   // end > beg (self-loop)
    float d0 = 0.f, d1 = 0.f, d2 = 0.f, d3 = 0.f;
    float n0 = 0.f, n1 = 0.f, n2 = 0.f, n3 = 0.f;
    for (int e = beg; e < end; ++e) {
      int src = col[e];
      float4 as4 = *(const float4*)(a_s + (long long)src * 4);
      const float* hp = hl + (long long)src * 256;
      float h0 = hp[0], h1 = hp[64], h2 = hp[128], h3 = hp[192];
      float l0 = as4.x + ad4.x; l0 = fmaxf(l0, NEG_SLOPE * l0);
      float l1 = as4.y + ad4.y; l1 = fmaxf(l1, NEG_SLOPE * l1);
      float l2 = as4.z + ad4.z; l2 = fmaxf(l2, NEG_SLOPE * l2);
      float l3 = as4.w + ad4.w; l3 = fmaxf(l3, NEG_SLOPE * l3);
      float s0 = __expf(l0), s1 = __expf(l1), s2 = __expf(l2), s3 = __expf(l3);
      d0 += s0; d1 += s1; d2 += s2; d3 += s3;
      n0 = fmaf(s0, h0, n0); n1 = fmaf(s1, h1, n1);
      n2 = fmaf(s2, h2, n2); n3 = fmaf(s3, h3, n3);
    }
    float v = 0.25f * (n0 / (d0 + 1e-16f) + n1 / (d1 + 1e-16f) +
                       n2 / (d2 + 1e-16f) + n3 / (d3 + 1e-16f));
    long long b = load_idx(batch, n, is64);
    v += cb + tpo[b * 64 + lane];
    float t1 = v, t2 = v * v;
#pragma unroll
    for (int m = 32; m; m >>= 1) {
      t1 += __shfl_xor(t1, m, 64);
      t2 += __shfl_xor(t2, m, 64);
    }
    float mean = t1 * (1.f / 64.f);
    float var  = t2 * (1.f / 64.f) - mean * mean;
    float y = (v - mean) * rsqrtf(var + LN_EPS) * gg + bb;
    out[n * 64 + lane] = y / (1.f + __expf(-y));
  }
}

// ----------------------------------------------------------------------------
extern "C" void kernel_launch(void* const* d_in, const int* in_sizes, int n_in,
                              void* d_out, int out_size, void* d_ws, size_t ws_size,
                              hipStream_t stream) {
  const float* x        = (const float*)d_in[0];
  const void*  ei       = d_in[1];
  const float* time_emb = (const float*)d_in[2];
  const void*  batch    = d_in[3];
  const float* W        = (const float*)d_in[4];
  const float* att_src  = (const float*)d_in[5];
  const float* att_dst  = (const float*)d_in[6];
  const float* conv_b   = (const float*)d_in[7];
  const float* tp_w     = (const float*)d_in[8];
  const float* tp_b     = (const float*)d_in[9];
  const float* ln_g     = (const float*)d_in[10];
  const float* ln_b     = (const float*)d_in[11];

  long long N = in_sizes[0] / 128;   // 50000
  long long E = in_sizes[1] / 2;     // 800000
  long long B = in_sizes[2] / 128;   // 16
  long long Etot = E + N;
  long long SC = ((N + 4095) / 4096) * 4096;   // scan-padded length

  // workspace layout (256B-aligned chunks), ~57 MB total
  char* p = (char*)d_ws;
  int*   flag   = (int*)p;   p += 256;
  float* h      = (float*)p; p += (size_t)N * 256 * 4;     // 51.2 MB
  float* a_s    = (float*)p; p += (size_t)N * 4 * 4;       // 800 KB
  float* a_d    = (float*)p; p += (size_t)N * 4 * 4;       // 800 KB
  int*   cnt    = (int*)p;   p += (size_t)SC * 4;          // padded
  int*   rowptr = (int*)p;   p += (size_t)(SC + 64) * 4;   // padded
  int*   cursor = (int*)p;   p += (size_t)SC * 4;          // padded
  int*   col    = (int*)p;   p += (size_t)Etot * 4;        // 3.4 MB
  float* tpo    = (float*)p; p += (size_t)B * 64 * 4;      // 4 KB

  hipMemsetAsync(cnt, 0, (size_t)SC * 4, stream);

  k_detect<<<dim3(1), 64, 0, stream>>>(ei, E, N, flag);
  k_gemm<<<dim3((unsigned)((N + 63) / 64)), 256, 0, stream>>>(x, W, att_src, att_dst,
                                                              h, a_s, a_d, (int)N);
  k_tp<<<dim3((unsigned)((B * 64 + 255) / 256)), 256, 0, stream>>>(time_emb, tp_w, tp_b, tpo, (int)B);
  k_hist<<<dim3(2048), 256, 0, stream>>>(ei, flag, cnt, E, N);
  k_scan<<<dim3(1), 1024, 0, stream>>>(cnt, rowptr, cursor, (int)N, (int)SC);
  k_scatter<<<dim3(2048), 256, 0, stream>>>(ei, flag, cursor, col, E, N);
  k_agg_csr<<<dim3(2048), 256, 0, stream>>>(rowptr, col, a_s, a_d, h, conv_b, tpo,
                                            batch, flag, ln_g, ln_b, (float*)d_out, N);
}

// Round 6
// 405.165 us; speedup vs baseline: 1.2166x; 1.1258x over previous
//
#include <hip/hip_runtime.h>
#include <math.h>

// GraphDiffusionBlock: GAT(4 heads x 64ch) + time-proj + LayerNorm + SiLU
// Pipeline: detect idx dtype -> W transpose -> GEMM h=xWT (+fused att logits,
//           coalesced WT loads) -> time proj -> CSR-by-dst build -> fused
//           aggregate+epilogue (register accumulation, NO f32 atomics).
// Softmax without max-shift (shift-invariant; logits ~N(0,1.3), max ~6 -> exp safe).

#define LN_EPS 1e-5f
#define NEG_SLOPE 0.2f

// ---------------------------------------------------------------- dtype detect
__global__ void k_detect(const void* __restrict__ idx, long long n64, long long maxval,
                         int* __restrict__ flag) {
  int lane = threadIdx.x;
  long long cnt = n64 < 64 ? n64 : 64;
  int bad = 0;
  if (lane < cnt) {
    long long v = ((const long long*)idx)[lane];
    bad = (v < 0 || v >= maxval) ? 1 : 0;
  }
  unsigned long long m = __ballot(bad);
  if (lane == 0) *flag = (m == 0ULL) ? 1 : 0;
}

__device__ __forceinline__ long long load_idx(const void* p, long long i, int is64) {
  return is64 ? ((const long long*)p)[i] : (long long)((const int*)p)[i];
}

// ---------------------------------------------------------------- W transpose
// WT[k][c] = W[c][k].  W:[256][128] -> WT:[128][256].  Coalesced read; the
// scattered write is only 131 KB (~3us). Makes GEMM W-loads fully coalesced.
__global__ __launch_bounds__(256) void k_wt(const float* __restrict__ W,
                                            float* __restrict__ WT) {
  int i = blockIdx.x * 256 + threadIdx.x;   // 32768 elements
  int c = i >> 7, k = i & 127;
  WT[k * 256 + c] = W[i];
}

// ---------------------------------------------------------------- GEMM h = x @ W^T  (+ att logits)
// x:[N,128], WT:[128][256] -> h:[N,256] ([N][head][64ch] layout).
// Thread (w=tid>>6 -> nodes w*16..w*16+15, c=tid&63 -> channels 4c..4c+3).
// Per 4-k: 4 coalesced WT float4 loads (lane-consecutive, L2-hot) +
// 16 LDS float4 broadcasts + 256 FMAs -> FMA-issue-bound (~21us floor).
// Fused attention logits: head = c>>4, reduce within 16-lane groups.
__global__ __launch_bounds__(256) void k_gemm(const float* __restrict__ x,
                                              const float* __restrict__ WT,
                                              const float* __restrict__ att_src,
                                              const float* __restrict__ att_dst,
                                              float* __restrict__ h,
                                              float* __restrict__ a_s,
                                              float* __restrict__ a_d, int N) {
  __shared__ float xs[64][128];
  int n0 = blockIdx.x * 64;
  int tid = threadIdx.x;
  for (int i = tid; i < 64 * 32; i += 256) {   // stage x tile (2048 float4)
    int n = i >> 5;
    int k4 = i & 31;
    float4 v = make_float4(0.f, 0.f, 0.f, 0.f);
    if (n0 + n < N) v = reinterpret_cast<const float4*>(x)[(long long)(n0 + n) * 32 + k4];
    reinterpret_cast<float4*>(&xs[n][0])[k4] = v;
  }
  __syncthreads();

  int c = tid & 63;          // channel-quad id: global channels 4c..4c+3
  int w = tid >> 6;          // wave -> nodes [w*16, w*16+16)
  int nbase = w * 16;
  const float4* wt4 = reinterpret_cast<const float4*>(WT) + c;   // row k: wt4[k*64]

  float4 acc[16];
#pragma unroll
  for (int i = 0; i < 16; ++i) acc[i] = make_float4(0.f, 0.f, 0.f, 0.f);

  for (int k = 0; k < 128; k += 4) {
    float4 w0 = wt4[(k + 0) * 64];
    float4 w1 = wt4[(k + 1) * 64];
    float4 w2 = wt4[(k + 2) * 64];
    float4 w3 = wt4[(k + 3) * 64];
#pragma unroll
    for (int i = 0; i < 16; ++i) {
      float4 xv = *(const float4*)(&xs[nbase + i][k]);
      acc[i].x += xv.x * w0.x + xv.y * w1.x + xv.z * w2.x + xv.w * w3.x;
      acc[i].y += xv.x * w0.y + xv.y * w1.y + xv.z * w2.y + xv.w * w3.y;
      acc[i].z += xv.x * w0.z + xv.y * w1.z + xv.z * w2.z + xv.w * w3.z;
      acc[i].w += xv.x * w0.w + xv.y * w1.w + xv.z * w2.w + xv.w * w3.w;
    }
  }

  // attention vectors for this thread's 4 channels (head hh, in-head base cb)
  int hh = c >> 4;
  int cb = 4 * (c & 15);
  float as0 = att_src[hh * 64 + cb + 0], as1 = att_src[hh * 64 + cb + 1];
  float as2 = att_src[hh * 64 + cb + 2], as3 = att_src[hh * 64 + cb + 3];
  float ad0 = att_dst[hh * 64 + cb + 0], ad1 = att_dst[hh * 64 + cb + 1];
  float ad2 = att_dst[hh * 64 + cb + 2], ad3 = att_dst[hh * 64 + cb + 3];

#pragma unroll
  for (int i = 0; i < 16; ++i) {
    int n = n0 + nbase + i;
    float rs = acc[i].x * as0 + acc[i].y * as1 + acc[i].z * as2 + acc[i].w * as3;
    float rd = acc[i].x * ad0 + acc[i].y * ad1 + acc[i].z * ad2 + acc[i].w * ad3;
#pragma unroll
    for (int m = 1; m < 16; m <<= 1) {   // reduce within 16-lane group (= one head)
      rs += __shfl_xor(rs, m, 64);
      rd += __shfl_xor(rd, m, 64);
    }
    if (n < N) {
      *(float4*)(&h[(long long)n * 256 + 4 * c]) = acc[i];   // 1KB coalesced wave-store
      if ((c & 15) == 0) {
        a_s[(long long)n * 4 + hh] = rs;
        a_d[(long long)n * 4 + hh] = rd;
      }
    }
  }
}

// ---------------------------------------------------------------- time projection
__global__ void k_tp(const float* __restrict__ time_emb, const float* __restrict__ tp_w,
                     const float* __restrict__ tp_b, float* __restrict__ tp, int B) {
  int tid = blockIdx.x * blockDim.x + threadIdx.x;
  if (tid >= B * 64) return;
  int b = tid >> 6, c = tid & 63;
  const float* te = time_emb + (long long)b * 128;
  const float* wr = tp_w + (long long)c * 128;
  float s = 0.f;
  for (int k = 0; k < 128; ++k) {
    float t = te[k];
    s += (t / (1.f + __expf(-t))) * wr[k];
  }
  tp[tid] = s + tp_b[c];
}

// ---------------------------------------------------------------- CSR build: hist
__global__ __launch_bounds__(256) void k_hist(const void* __restrict__ ei,
                                              const int* __restrict__ flag,
                                              int* __restrict__ cnt,
                                              long long E, long long N) {
  long long Etot = E + N;
  int is64 = *flag;
  for (long long e = blockIdx.x * (long long)blockDim.x + threadIdx.x; e < Etot;
       e += (long long)gridDim.x * blockDim.x) {
    long long dst = (e < E) ? load_idx(ei, E + e, is64) : (e - E);
    atomicAdd(cnt + dst, 1);
  }
}

// ---------------------------------------------------------------- CSR build: scan
__global__ __launch_bounds__(1024) void k_scan(const int* __restrict__ cnt,
                                               int* __restrict__ rowptr,
                                               int* __restrict__ cursor, int N, int SC) {
  __shared__ int wsum[16];
  __shared__ int carry_sm;
  int tid = threadIdx.x, lane = tid & 63, w = tid >> 6;
  if (tid == 0) carry_sm = 0;
  __syncthreads();
  int nchunk = SC / 4096;
  for (int c = 0; c < nchunk; ++c) {
    int base = c * 4096 + tid * 4;
    int4 v = *(const int4*)(cnt + base);
    int t0 = v.x, t1 = t0 + v.y, t2 = t1 + v.z, t3 = t2 + v.w;
    int s = t3;                                   // thread total
#pragma unroll
    for (int off = 1; off < 64; off <<= 1) {      // wave inclusive scan
      int t = __shfl_up(s, off, 64);
      if (lane >= off) s += t;
    }
    if (lane == 63) wsum[w] = s;
    __syncthreads();
    if (w == 0) {                                 // scan the 16 wave totals
      int t = (lane < 16) ? wsum[lane] : 0;
#pragma unroll
      for (int off = 1; off < 16; off <<= 1) {
        int u = __shfl_up(t, off, 64);
        if (lane >= off) t += u;
      }
      if (lane < 16) wsum[lane] = t;
    }
    __syncthreads();
    int woff = (w == 0) ? 0 : wsum[w - 1];
    int e0 = carry_sm + woff + (s - t3);          // exclusive prefix of v.x
    int4 ov = make_int4(e0, e0 + t0, e0 + t1, e0 + t2);
    *(int4*)(rowptr + base) = ov;
    *(int4*)(cursor + base) = ov;
    __syncthreads();
    if (tid == 0) carry_sm += wsum[15];
    __syncthreads();
  }
  if (tid == 0) rowptr[N] = carry_sm;
}

// ---------------------------------------------------------------- CSR build: scatter
__global__ __launch_bounds__(256) void k_scatter(const void* __restrict__ ei,
                                                 const int* __restrict__ flag,
                                                 int* __restrict__ cursor,
                                                 int* __restrict__ col,
                                                 long long E, long long N) {
  long long Etot = E + N;
  int is64 = *flag;
  for (long long e = blockIdx.x * (long long)blockDim.x + threadIdx.x; e < Etot;
       e += (long long)gridDim.x * blockDim.x) {
    long long src, dst;
    if (e < E) { src = load_idx(ei, e, is64); dst = load_idx(ei, E + e, is64); }
    else       { src = dst = e - E; }
    int pos = atomicAdd(cursor + dst, 1);
    col[pos] = (int)src;
  }
}

// ---------------------------------------------------------------- fused aggregate + epilogue
// Grid-stride wave per dst node; __expf, fmax leaky-relu, fma accumulation;
// h rows gathered coalesced (4x256B per edge, L3-hot); LayerNorm+SiLU fused.
__global__ __launch_bounds__(256) void k_agg_csr(const int* __restrict__ rowptr,
                                                 const int* __restrict__ col,
                                                 const float* __restrict__ a_s,
                                                 const float* __restrict__ a_d,
                                                 const float* __restrict__ h,
                                                 const float* __restrict__ conv_bias,
                                                 const float* __restrict__ tpo,
                                                 const void* __restrict__ batch,
                                                 const int* __restrict__ flag,
                                                 const float* __restrict__ ln_g,
                                                 const float* __restrict__ ln_b,
                                                 float* __restrict__ out, long long N) {
  int lane = threadIdx.x & 63;
  int is64 = *flag;
  long long wid = ((long long)blockIdx.x * blockDim.x + threadIdx.x) >> 6;
  long long nw  = ((long long)gridDim.x * blockDim.x) >> 6;
  float cb = conv_bias[lane];
  float gg = ln_g[lane], bb = ln_b[lane];
  const float* hl = h + lane;

  for (long long n = wid; n < N; n += nw) {
    float4 ad4 = *(const float4*)(a_d + n * 4);
    int beg = rowptr[n], end = rowptr[n + 1];   // end > beg (self-loop)
    float d0 = 0.f, d1 = 0.f, d2 = 0.f, d3 = 0.f;
    float n0 = 0.f, n1 = 0.f, n2 = 0.f, n3 = 0.f;
    for (int e = beg; e < end; ++e) {
      int src = col[e];
      float4 as4 = *(const float4*)(a_s + (long long)src * 4);
      const float* hp = hl + (long long)src * 256;
      float h0 = hp[0], h1 = hp[64], h2 = hp[128], h3 = hp[192];
      float l0 = as4.x + ad4.x; l0 = fmaxf(l0, NEG_SLOPE * l0);
      float l1 = as4.y + ad4.y; l1 = fmaxf(l1, NEG_SLOPE * l1);
      float l2 = as4.z + ad4.z; l2 = fmaxf(l2, NEG_SLOPE * l2);
      float l3 = as4.w + ad4.w; l3 = fmaxf(l3, NEG_SLOPE * l3);
      float s0 = __expf(l0), s1 = __expf(l1), s2 = __expf(l2), s3 = __expf(l3);
      d0 += s0; d1 += s1; d2 += s2; d3 += s3;
      n0 = fmaf(s0, h0, n0); n1 = fmaf(s1, h1, n1);
      n2 = fmaf(s2, h2, n2); n3 = fmaf(s3, h3, n3);
    }
    float v = 0.25f * (n0 / (d0 + 1e-16f) + n1 / (d1 + 1e-16f) +
                       n2 / (d2 + 1e-16f) + n3 / (d3 + 1e-16f));
    long long b = load_idx(batch, n, is64);
    v += cb + tpo[b * 64 + lane];
    float t1 = v, t2 = v * v;
#pragma unroll
    for (int m = 32; m; m >>= 1) {
      t1 += __shfl_xor(t1, m, 64);
      t2 += __shfl_xor(t2, m, 64);
    }
    float mean = t1 * (1.f / 64.f);
    float var  = t2 * (1.f / 64.f) - mean * mean;
    float y = (v - mean) * rsqrtf(var + LN_EPS) * gg + bb;
    out[n * 64 + lane] = y / (1.f + __expf(-y));
  }
}

// ----------------------------------------------------------------------------
extern "C" void kernel_launch(void* const* d_in, const int* in_sizes, int n_in,
                              void* d_out, int out_size, void* d_ws, size_t ws_size,
                              hipStream_t stream) {
  const float* x        = (const float*)d_in[0];
  const void*  ei       = d_in[1];
  const float* time_emb = (const float*)d_in[2];
  const void*  batch    = d_in[3];
  const float* W        = (const float*)d_in[4];
  const float* att_src  = (const float*)d_in[5];
  const float* att_dst  = (const float*)d_in[6];
  const float* conv_b   = (const float*)d_in[7];
  const float* tp_w     = (const float*)d_in[8];
  const float* tp_b     = (const float*)d_in[9];
  const float* ln_g     = (const float*)d_in[10];
  const float* ln_b     = (const float*)d_in[11];

  long long N = in_sizes[0] / 128;   // 50000
  long long E = in_sizes[1] / 2;     // 800000
  long long B = in_sizes[2] / 128;   // 16
  long long Etot = E + N;
  long long SC = ((N + 4095) / 4096) * 4096;   // scan-padded length

  // workspace layout (256B-aligned chunks), ~57 MB total
  char* p = (char*)d_ws;
  int*   flag   = (int*)p;   p += 256;
  float* h      = (float*)p; p += (size_t)N * 256 * 4;     // 51.2 MB
  float* WT     = (float*)p; p += (size_t)128 * 256 * 4;   // 131 KB
  float* a_s    = (float*)p; p += (size_t)N * 4 * 4;       // 800 KB
  float* a_d    = (float*)p; p += (size_t)N * 4 * 4;       // 800 KB
  int*   cnt    = (int*)p;   p += (size_t)SC * 4;          // padded
  int*   rowptr = (int*)p;   p += (size_t)(SC + 64) * 4;   // padded
  int*   cursor = (int*)p;   p += (size_t)SC * 4;          // padded
  int*   col    = (int*)p;   p += (size_t)Etot * 4;        // 3.4 MB
  float* tpo    = (float*)p; p += (size_t)B * 64 * 4;      // 4 KB

  hipMemsetAsync(cnt, 0, (size_t)SC * 4, stream);

  k_detect<<<dim3(1), 64, 0, stream>>>(ei, E, N, flag);
  k_wt<<<dim3(128), 256, 0, stream>>>(W, WT);
  k_gemm<<<dim3((unsigned)((N + 63) / 64)), 256, 0, stream>>>(x, WT, att_src, att_dst,
                                                              h, a_s, a_d, (int)N);
  k_tp<<<dim3((unsigned)((B * 64 + 255) / 256)), 256, 0, stream>>>(time_emb, tp_w, tp_b, tpo, (int)B);
  k_hist<<<dim3(2048), 256, 0, stream>>>(ei, flag, cnt, E, N);
  k_scan<<<dim3(1), 1024, 0, stream>>>(cnt, rowptr, cursor, (int)N, (int)SC);
  k_scatter<<<dim3(2048), 256, 0, stream>>>(ei, flag, cursor, col, E, N);
  k_agg_csr<<<dim3(2048), 256, 0, stream>>>(rowptr, col, a_s, a_d, h, conv_b, tpo,
                                            batch, flag, ln_g, ln_b, (float*)d_out, N);
}

// Round 8
// 403.211 us; speedup vs baseline: 1.2225x; 1.0048x over previous
//
#include <hip/hip_runtime.h>
#include <math.h>

// GraphDiffusionBlock: GAT(4 heads x 64ch) + time-proj + LayerNorm + SiLU
// Pipeline: detect idx dtype -> W transpose -> GEMM h=xWT (+fused att logits,
//           coalesced WT loads) -> time proj -> CSR-by-dst build -> fused
//           aggregate+epilogue (register accumulation, NO f32 atomics,
//           4-edge software pipeline for gather MLP).
// Softmax without max-shift (shift-invariant; logits ~N(0,1.3), max ~6 -> exp safe).

#define LN_EPS 1e-5f
#define NEG_SLOPE 0.2f

// ---------------------------------------------------------------- dtype detect
__global__ void k_detect(const void* __restrict__ idx, long long n64, long long maxval,
                         int* __restrict__ flag) {
  int lane = threadIdx.x;
  long long cnt = n64 < 64 ? n64 : 64;
  int bad = 0;
  if (lane < cnt) {
    long long v = ((const long long*)idx)[lane];
    bad = (v < 0 || v >= maxval) ? 1 : 0;
  }
  unsigned long long m = __ballot(bad);
  if (lane == 0) *flag = (m == 0ULL) ? 1 : 0;
}

__device__ __forceinline__ long long load_idx(const void* p, long long i, int is64) {
  return is64 ? ((const long long*)p)[i] : (long long)((const int*)p)[i];
}

// ---------------------------------------------------------------- W transpose
__global__ __launch_bounds__(256) void k_wt(const float* __restrict__ W,
                                            float* __restrict__ WT) {
  int i = blockIdx.x * 256 + threadIdx.x;   // 32768 elements
  int c = i >> 7, k = i & 127;
  WT[k * 256 + c] = W[i];
}

// ---------------------------------------------------------------- GEMM h = x @ W^T  (+ att logits)
// Thread (w=tid>>6 -> nodes w*16..w*16+15, c=tid&63 -> channels 4c..4c+3).
// Per 4-k: 4 coalesced WT float4 loads + 16 LDS broadcasts + 256 FMAs.
__global__ __launch_bounds__(256) void k_gemm(const float* __restrict__ x,
                                              const float* __restrict__ WT,
                                              const float* __restrict__ att_src,
                                              const float* __restrict__ att_dst,
                                              float* __restrict__ h,
                                              float* __restrict__ a_s,
                                              float* __restrict__ a_d, int N) {
  __shared__ float xs[64][128];
  int n0 = blockIdx.x * 64;
  int tid = threadIdx.x;
  for (int i = tid; i < 64 * 32; i += 256) {   // stage x tile (2048 float4)
    int n = i >> 5;
    int k4 = i & 31;
    float4 v = make_float4(0.f, 0.f, 0.f, 0.f);
    if (n0 + n < N) v = reinterpret_cast<const float4*>(x)[(long long)(n0 + n) * 32 + k4];
    reinterpret_cast<float4*>(&xs[n][0])[k4] = v;
  }
  __syncthreads();

  int c = tid & 63;          // channel-quad id: global channels 4c..4c+3
  int w = tid >> 6;          // wave -> nodes [w*16, w*16+16)
  int nbase = w * 16;
  const float4* wt4 = reinterpret_cast<const float4*>(WT) + c;   // row k: wt4[k*64]

  float4 acc[16];
#pragma unroll
  for (int i = 0; i < 16; ++i) acc[i] = make_float4(0.f, 0.f, 0.f, 0.f);

  for (int k = 0; k < 128; k += 4) {
    float4 w0 = wt4[(k + 0) * 64];
    float4 w1 = wt4[(k + 1) * 64];
    float4 w2 = wt4[(k + 2) * 64];
    float4 w3 = wt4[(k + 3) * 64];
#pragma unroll
    for (int i = 0; i < 16; ++i) {
      float4 xv = *(const float4*)(&xs[nbase + i][k]);
      acc[i].x += xv.x * w0.x + xv.y * w1.x + xv.z * w2.x + xv.w * w3.x;
      acc[i].y += xv.x * w0.y + xv.y * w1.y + xv.z * w2.y + xv.w * w3.y;
      acc[i].z += xv.x * w0.z + xv.y * w1.z + xv.z * w2.z + xv.w * w3.z;
      acc[i].w += xv.x * w0.w + xv.y * w1.w + xv.z * w2.w + xv.w * w3.w;
    }
  }

  int hh = c >> 4;
  int cb = 4 * (c & 15);
  float as0 = att_src[hh * 64 + cb + 0], as1 = att_src[hh * 64 + cb + 1];
  float as2 = att_src[hh * 64 + cb + 2], as3 = att_src[hh * 64 + cb + 3];
  float ad0 = att_dst[hh * 64 + cb + 0], ad1 = att_dst[hh * 64 + cb + 1];
  float ad2 = att_dst[hh * 64 + cb + 2], ad3 = att_dst[hh * 64 + cb + 3];

#pragma unroll
  for (int i = 0; i < 16; ++i) {
    int n = n0 + nbase + i;
    float rs = acc[i].x * as0 + acc[i].y * as1 + acc[i].z * as2 + acc[i].w * as3;
    float rd = acc[i].x * ad0 + acc[i].y * ad1 + acc[i].z * ad2 + acc[i].w * ad3;
#pragma unroll
    for (int m = 1; m < 16; m <<= 1) {   // reduce within 16-lane group (= one head)
      rs += __shfl_xor(rs, m, 64);
      rd += __shfl_xor(rd, m, 64);
    }
    if (n < N) {
      *(float4*)(&h[(long long)n * 256 + 4 * c]) = acc[i];   // 1KB coalesced wave-store
      if ((c & 15) == 0) {
        a_s[(long long)n * 4 + hh] = rs;
        a_d[(long long)n * 4 + hh] = rd;
      }
    }
  }
}

// ---------------------------------------------------------------- time projection
__global__ void k_tp(const float* __restrict__ time_emb, const float* __restrict__ tp_w,
                     const float* __restrict__ tp_b, float* __restrict__ tp, int B) {
  int tid = blockIdx.x * blockDim.x + threadIdx.x;
  if (tid >= B * 64) return;
  int b = tid >> 6, c = tid & 63;
  const float* te = time_emb + (long long)b * 128;
  const float* wr = tp_w + (long long)c * 128;
  float s = 0.f;
  for (int k = 0; k < 128; ++k) {
    float t = te[k];
    s += (t / (1.f + __expf(-t))) * wr[k];
  }
  tp[tid] = s + tp_b[c];
}

// ---------------------------------------------------------------- CSR build: hist
__global__ __launch_bounds__(256) void k_hist(const void* __restrict__ ei,
                                              const int* __restrict__ flag,
                                              int* __restrict__ cnt,
                                              long long E, long long N) {
  long long Etot = E + N;
  int is64 = *flag;
  for (long long e = blockIdx.x * (long long)blockDim.x + threadIdx.x; e < Etot;
       e += (long long)gridDim.x * blockDim.x) {
    long long dst = (e < E) ? load_idx(ei, E + e, is64) : (e - E);
    atomicAdd(cnt + dst, 1);
  }
}

// ---------------------------------------------------------------- CSR build: scan
__global__ __launch_bounds__(1024) void k_scan(const int* __restrict__ cnt,
                                               int* __restrict__ rowptr,
                                               int* __restrict__ cursor, int N, int SC) {
  __shared__ int wsum[16];
  __shared__ int carry_sm;
  int tid = threadIdx.x, lane = tid & 63, w = tid >> 6;
  if (tid == 0) carry_sm = 0;
  __syncthreads();
  int nchunk = SC / 4096;
  for (int c = 0; c < nchunk; ++c) {
    int base = c * 4096 + tid * 4;
    int4 v = *(const int4*)(cnt + base);
    int t0 = v.x, t1 = t0 + v.y, t2 = t1 + v.z, t3 = t2 + v.w;
    int s = t3;                                   // thread total
#pragma unroll
    for (int off = 1; off < 64; off <<= 1) {      // wave inclusive scan
      int t = __shfl_up(s, off, 64);
      if (lane >= off) s += t;
    }
    if (lane == 63) wsum[w] = s;
    __syncthreads();
    if (w == 0) {                                 // scan the 16 wave totals
      int t = (lane < 16) ? wsum[lane] : 0;
#pragma unroll
      for (int off = 1; off < 16; off <<= 1) {
        int u = __shfl_up(t, off, 64);
        if (lane >= off) t += u;
      }
      if (lane < 16) wsum[lane] = t;
    }
    __syncthreads();
    int woff = (w == 0) ? 0 : wsum[w - 1];
    int e0 = carry_sm + woff + (s - t3);          // exclusive prefix of v.x
    int4 ov = make_int4(e0, e0 + t0, e0 + t1, e0 + t2);
    *(int4*)(rowptr + base) = ov;
    *(int4*)(cursor + base) = ov;
    __syncthreads();
    if (tid == 0) carry_sm += wsum[15];
    __syncthreads();
  }
  if (tid == 0) rowptr[N] = carry_sm;
}

// ---------------------------------------------------------------- CSR build: scatter
__global__ __launch_bounds__(256) void k_scatter(const void* __restrict__ ei,
                                                 const int* __restrict__ flag,
                                                 int* __restrict__ cursor,
                                                 int* __restrict__ col,
                                                 long long E, long long N) {
  long long Etot = E + N;
  int is64 = *flag;
  for (long long e = blockIdx.x * (long long)blockDim.x + threadIdx.x; e < Etot;
       e += (long long)gridDim.x * blockDim.x) {
    long long src, dst;
    if (e < E) { src = load_idx(ei, e, is64); dst = load_idx(ei, E + e, is64); }
    else       { src = dst = e - E; }
    int pos = atomicAdd(cursor + dst, 1);
    col[pos] = (int)src;
  }
}

// ---------------------------------------------------------------- fused aggregate + epilogue
// Grid-stride wave per dst node. 4-edge software pipeline: all 20 gather loads
// (4 as4 + 16 h) issue before any consumption -> ~4x MLP vs serial edge loop
// (round-6 evidence: VALUBusy 42%, occ 75% -> gather-latency-bound).
// Accumulators stay sequential in e-order (numerics unchanged).
__global__ __launch_bounds__(256) void k_agg_csr(const int* __restrict__ rowptr,
                                                 const int* __restrict__ col,
                                                 const float* __restrict__ a_s,
                                                 const float* __restrict__ a_d,
                                                 const float* __restrict__ h,
                                                 const float* __restrict__ conv_bias,
                                                 const float* __restrict__ tpo,
                                                 const void* __restrict__ batch,
                                                 const int* __restrict__ flag,
                                                 const float* __restrict__ ln_g,
                                                 const float* __restrict__ ln_b,
                                                 float* __restrict__ out, long long N) {
  int lane = threadIdx.x & 63;
  int is64 = *flag;
  long long wid = ((long long)blockIdx.x * blockDim.x + threadIdx.x) >> 6;
  long long nw  = ((long long)gridDim.x * blockDim.x) >> 6;
  float cb = conv_bias[lane];
  float gg = ln_g[lane], bb = ln_b[lane];
  const float* hl = h + lane;

  for (long long n = wid; n < N; n += nw) {
    float4 ad4 = *(const float4*)(a_d + n * 4);
    int beg = rowptr[n], end = rowptr[n + 1];   // end > beg (self-loop)
    float d0 = 0.f, d1 = 0.f, d2 = 0.f, d3 = 0.f;
    float n0 = 0.f, n1 = 0.f, n2 = 0.f, n3 = 0.f;
    int e = beg;
    for (; e + 3 < end; e += 4) {               // 4-edge pipelined body
      int s0 = col[e], s1 = col[e + 1], s2 = col[e + 2], s3 = col[e + 3];
      float4 A0 = *(const float4*)(a_s + (long long)s0 * 4);
      float4 A1 = *(const float4*)(a_s + (long long)s1 * 4);
      float4 A2 = *(const float4*)(a_s + (long long)s2 * 4);
      float4 A3 = *(const float4*)(a_s + (long long)s3 * 4);
      const float* p0 = hl + (long long)s0 * 256;
      const float* p1 = hl + (long long)s1 * 256;
      const float* p2 = hl + (long long)s2 * 256;
      const float* p3 = hl + (long long)s3 * 256;
      float h00 = p0[0], h01 = p0[64], h02 = p0[128], h03 = p0[192];
      float h10 = p1[0], h11 = p1[64], h12 = p1[128], h13 = p1[192];
      float h20 = p2[0], h21 = p2[64], h22 = p2[128], h23 = p2[192];
      float h30 = p3[0], h31 = p3[64], h32 = p3[128], h33 = p3[192];

      float l0, l1, l2, l3, x0, x1, x2, x3;
      l0 = A0.x + ad4.x; l1 = A0.y + ad4.y; l2 = A0.z + ad4.z; l3 = A0.w + ad4.w;
      l0 = fmaxf(l0, NEG_SLOPE * l0); l1 = fmaxf(l1, NEG_SLOPE * l1);
      l2 = fmaxf(l2, NEG_SLOPE * l2); l3 = fmaxf(l3, NEG_SLOPE * l3);
      x0 = __expf(l0); x1 = __expf(l1); x2 = __expf(l2); x3 = __expf(l3);
      d0 += x0; d1 += x1; d2 += x2; d3 += x3;
      n0 = fmaf(x0, h00, n0); n1 = fmaf(x1, h01, n1);
      n2 = fmaf(x2, h02, n2); n3 = fmaf(x3, h03, n3);

      l0 = A1.x + ad4.x; l1 = A1.y + ad4.y; l2 = A1.z + ad4.z; l3 = A1.w + ad4.w;
      l0 = fmaxf(l0, NEG_SLOPE * l0); l1 = fmaxf(l1, NEG_SLOPE * l1);
      l2 = fmaxf(l2, NEG_SLOPE * l2); l3 = fmaxf(l3, NEG_SLOPE * l3);
      x0 = __expf(l0); x1 = __expf(l1); x2 = __expf(l2); x3 = __expf(l3);
      d0 += x0; d1 += x1; d2 += x2; d3 += x3;
      n0 = fmaf(x0, h10, n0); n1 = fmaf(x1, h11, n1);
      n2 = fmaf(x2, h12, n2); n3 = fmaf(x3, h13, n3);

      l0 = A2.x + ad4.x; l1 = A2.y + ad4.y; l2 = A2.z + ad4.z; l3 = A2.w + ad4.w;
      l0 = fmaxf(l0, NEG_SLOPE * l0); l1 = fmaxf(l1, NEG_SLOPE * l1);
      l2 = fmaxf(l2, NEG_SLOPE * l2); l3 = fmaxf(l3, NEG_SLOPE * l3);
      x0 = __expf(l0); x1 = __expf(l1); x2 = __expf(l2); x3 = __expf(l3);
      d0 += x0; d1 += x1; d2 += x2; d3 += x3;
      n0 = fmaf(x0, h20, n0); n1 = fmaf(x1, h21, n1);
      n2 = fmaf(x2, h22, n2); n3 = fmaf(x3, h23, n3);

      l0 = A3.x + ad4.x; l1 = A3.y + ad4.y; l2 = A3.z + ad4.z; l3 = A3.w + ad4.w;
      l0 = fmaxf(l0, NEG_SLOPE * l0); l1 = fmaxf(l1, NEG_SLOPE * l1);
      l2 = fmaxf(l2, NEG_SLOPE * l2); l3 = fmaxf(l3, NEG_SLOPE * l3);
      x0 = __expf(l0); x1 = __expf(l1); x2 = __expf(l2); x3 = __expf(l3);
      d0 += x0; d1 += x1; d2 += x2; d3 += x3;
      n0 = fmaf(x0, h30, n0); n1 = fmaf(x1, h31, n1);
      n2 = fmaf(x2, h32, n2); n3 = fmaf(x3, h33, n3);
    }
    for (; e < end; ++e) {                      // tail (<=3 edges)
      int src = col[e];
      float4 as4 = *(const float4*)(a_s + (long long)src * 4);
      const float* hp = hl + (long long)src * 256;
      float h0 = hp[0], h1 = hp[64], h2 = hp[128], h3 = hp[192];
      float l0 = as4.x + ad4.x; l0 = fmaxf(l0, NEG_SLOPE * l0);
      float l1 = as4.y + ad4.y; l1 = fmaxf(l1, NEG_SLOPE * l1);
      float l2 = as4.z + ad4.z; l2 = fmaxf(l2, NEG_SLOPE * l2);
      float l3 = as4.w + ad4.w; l3 = fmaxf(l3, NEG_SLOPE * l3);
      float s0 = __expf(l0), s1 = __expf(l1), s2 = __expf(l2), s3 = __expf(l3);
      d0 += s0; d1 += s1; d2 += s2; d3 += s3;
      n0 = fmaf(s0, h0, n0); n1 = fmaf(s1, h1, n1);
      n2 = fmaf(s2, h2, n2); n3 = fmaf(s3, h3, n3);
    }
    float v = 0.25f * (n0 / (d0 + 1e-16f) + n1 / (d1 + 1e-16f) +
                       n2 / (d2 + 1e-16f) + n3 / (d3 + 1e-16f));
    long long b = load_idx(batch, n, is64);
    v += cb + tpo[b * 64 + lane];
    float t1 = v, t2 = v * v;
#pragma unroll
    for (int m = 32; m; m >>= 1) {
      t1 += __shfl_xor(t1, m, 64);
      t2 += __shfl_xor(t2, m, 64);
    }
    float mean = t1 * (1.f / 64.f);
    float var  = t2 * (1.f / 64.f) - mean * mean;
    float y = (v - mean) * rsqrtf(var + LN_EPS) * gg + bb;
    out[n * 64 + lane] = y / (1.f + __expf(-y));
  }
}

// ----------------------------------------------------------------------------
extern "C" void kernel_launch(void* const* d_in, const int* in_sizes, int n_in,
                              void* d_out, int out_size, void* d_ws, size_t ws_size,
                              hipStream_t stream) {
  const float* x        = (const float*)d_in[0];
  const void*  ei       = d_in[1];
  const float* time_emb = (const float*)d_in[2];
  const void*  batch    = d_in[3];
  const float* W        = (const float*)d_in[4];
  const float* att_src  = (const float*)d_in[5];
  const float* att_dst  = (const float*)d_in[6];
  const float* conv_b   = (const float*)d_in[7];
  const float* tp_w     = (const float*)d_in[8];
  const float* tp_b     = (const float*)d_in[9];
  const float* ln_g     = (const float*)d_in[10];
  const float* ln_b     = (const float*)d_in[11];

  long long N = in_sizes[0] / 128;   // 50000
  long long E = in_sizes[1] / 2;     // 800000
  long long B = in_sizes[2] / 128;   // 16
  long long Etot = E + N;
  long long SC = ((N + 4095) / 4096) * 4096;   // scan-padded length

  // workspace layout (256B-aligned chunks), ~57 MB total
  char* p = (char*)d_ws;
  int*   flag   = (int*)p;   p += 256;
  float* h      = (float*)p; p += (size_t)N * 256 * 4;     // 51.2 MB
  float* WT     = (float*)p; p += (size_t)128 * 256 * 4;   // 131 KB
  float* a_s    = (float*)p; p += (size_t)N * 4 * 4;       // 800 KB
  float* a_d    = (float*)p; p += (size_t)N * 4 * 4;       // 800 KB
  int*   cnt    = (int*)p;   p += (size_t)SC * 4;          // padded
  int*   rowptr = (int*)p;   p += (size_t)(SC + 64) * 4;   // padded
  int*   cursor = (int*)p;   p += (size_t)SC * 4;          // padded
  int*   col    = (int*)p;   p += (size_t)Etot * 4;        // 3.4 MB
  float* tpo    = (float*)p; p += (size_t)B * 64 * 4;      // 4 KB

  hipMemsetAsync(cnt, 0, (size_t)SC * 4, stream);

  k_detect<<<dim3(1), 64, 0, stream>>>(ei, E, N, flag);
  k_wt<<<dim3(128), 256, 0, stream>>>(W, WT);
  k_gemm<<<dim3((unsigned)((N + 63) / 64)), 256, 0, stream>>>(x, WT, att_src, att_dst,
                                                              h, a_s, a_d, (int)N);
  k_tp<<<dim3((unsigned)((B * 64 + 255) / 256)), 256, 0, stream>>>(time_emb, tp_w, tp_b, tpo, (int)B);
  k_hist<<<dim3(2048), 256, 0, stream>>>(ei, flag, cnt, E, N);
  k_scan<<<dim3(1), 1024, 0, stream>>>(cnt, rowptr, cursor, (int)N, (int)SC);
  k_scatter<<<dim3(2048), 256, 0, stream>>>(ei, flag, cursor, col, E, N);
  k_agg_csr<<<dim3(2048), 256, 0, stream>>>(rowptr, col, a_s, a_d, h, conv_b, tpo,
                                            batch, flag, ln_g, ln_b, (float*)d_out, N);
}

// Round 10
// 372.907 us; speedup vs baseline: 1.3218x; 1.0813x over previous
//
#include <hip/hip_runtime.h>
#include <math.h>

// GraphDiffusionBlock: GAT(4 heads x 64ch) + time-proj + LayerNorm + SiLU
// Pipeline: detect idx dtype -> cvt edges to int32 -> W transpose ->
//           GEMM h=xWT (f32 logits, bf16 h store) -> time proj ->
//           CSR-by-dst build -> fused aggregate+epilogue (bf16 h gather,
//           register accumulation, NO f32 atomics, 4-edge pipeline).
// Round-8 evidence: agg gather path saturated at ~3.3 TB/s L2-miss rate
// (unroll neutral, VALUBusy 43%) -> halve bytes with bf16 h.

#define LN_EPS 1e-5f
#define NEG_SLOPE 0.2f

__device__ __forceinline__ unsigned short f2bf(float f) {   // RNE bf16
  unsigned int u = __float_as_uint(f);
  u += 0x7FFFu + ((u >> 16) & 1u);
  return (unsigned short)(u >> 16);
}
#define BF2F(v) __uint_as_float(((unsigned)(v)) << 16)

// ---------------------------------------------------------------- dtype detect
__global__ void k_detect(const void* __restrict__ idx, long long n64, long long maxval,
                         int* __restrict__ flag) {
  int lane = threadIdx.x;
  long long cnt = n64 < 64 ? n64 : 64;
  int bad = 0;
  if (lane < cnt) {
    long long v = ((const long long*)idx)[lane];
    bad = (v < 0 || v >= maxval) ? 1 : 0;
  }
  unsigned long long m = __ballot(bad);
  if (lane == 0) *flag = (m == 0ULL) ? 1 : 0;
}

__device__ __forceinline__ long long load_idx(const void* p, long long i, int is64) {
  return is64 ? ((const long long*)p)[i] : (long long)((const int*)p)[i];
}

// ---------------------------------------------------------------- edge cvt -> int32
// One pass: src32/dst32 (3.2MB each). Downstream passes read half the bytes
// and lose the per-element is64 branch.
__global__ __launch_bounds__(256) void k_cvt(const void* __restrict__ ei,
                                             const int* __restrict__ flag,
                                             int* __restrict__ src32,
                                             int* __restrict__ dst32, long long E) {
  long long i = (long long)blockIdx.x * blockDim.x + threadIdx.x;
  if (i >= E) return;
  int is64 = *flag;
  src32[i] = (int)load_idx(ei, i, is64);
  dst32[i] = (int)load_idx(ei, E + i, is64);
}

// ---------------------------------------------------------------- W transpose
__global__ __launch_bounds__(256) void k_wt(const float* __restrict__ W,
                                            float* __restrict__ WT) {
  int i = blockIdx.x * 256 + threadIdx.x;   // 32768 elements
  int c = i >> 7, k = i & 127;
  WT[k * 256 + c] = W[i];
}

// ---------------------------------------------------------------- GEMM h = x @ W^T  (+ att logits)
// Thread (w=tid>>6 -> nodes w*16..w*16+15, c=tid&63 -> channels 4c..4c+3).
// Logits from f32 accumulators (no quantization); h stored bf16 (RNE),
// wave-store 512B contiguous.
__global__ __launch_bounds__(256) void k_gemm(const float* __restrict__ x,
                                              const float* __restrict__ WT,
                                              const float* __restrict__ att_src,
                                              const float* __restrict__ att_dst,
                                              unsigned short* __restrict__ h,
                                              float* __restrict__ a_s,
                                              float* __restrict__ a_d, int N) {
  __shared__ float xs[64][128];
  int n0 = blockIdx.x * 64;
  int tid = threadIdx.x;
  for (int i = tid; i < 64 * 32; i += 256) {   // stage x tile (2048 float4)
    int n = i >> 5;
    int k4 = i & 31;
    float4 v = make_float4(0.f, 0.f, 0.f, 0.f);
    if (n0 + n < N) v = reinterpret_cast<const float4*>(x)[(long long)(n0 + n) * 32 + k4];
    reinterpret_cast<float4*>(&xs[n][0])[k4] = v;
  }
  __syncthreads();

  int c = tid & 63;          // channel-quad id: global channels 4c..4c+3
  int w = tid >> 6;          // wave -> nodes [w*16, w*16+16)
  int nbase = w * 16;
  const float4* wt4 = reinterpret_cast<const float4*>(WT) + c;   // row k: wt4[k*64]

  float4 acc[16];
#pragma unroll
  for (int i = 0; i < 16; ++i) acc[i] = make_float4(0.f, 0.f, 0.f, 0.f);

  for (int k = 0; k < 128; k += 4) {
    float4 w0 = wt4[(k + 0) * 64];
    float4 w1 = wt4[(k + 1) * 64];
    float4 w2 = wt4[(k + 2) * 64];
    float4 w3 = wt4[(k + 3) * 64];
#pragma unroll
    for (int i = 0; i < 16; ++i) {
      float4 xv = *(const float4*)(&xs[nbase + i][k]);
      acc[i].x += xv.x * w0.x + xv.y * w1.x + xv.z * w2.x + xv.w * w3.x;
      acc[i].y += xv.x * w0.y + xv.y * w1.y + xv.z * w2.y + xv.w * w3.y;
      acc[i].z += xv.x * w0.z + xv.y * w1.z + xv.z * w2.z + xv.w * w3.z;
      acc[i].w += xv.x * w0.w + xv.y * w1.w + xv.z * w2.w + xv.w * w3.w;
    }
  }

  int hh = c >> 4;
  int cb = 4 * (c & 15);
  float as0 = att_src[hh * 64 + cb + 0], as1 = att_src[hh * 64 + cb + 1];
  float as2 = att_src[hh * 64 + cb + 2], as3 = att_src[hh * 64 + cb + 3];
  float ad0 = att_dst[hh * 64 + cb + 0], ad1 = att_dst[hh * 64 + cb + 1];
  float ad2 = att_dst[hh * 64 + cb + 2], ad3 = att_dst[hh * 64 + cb + 3];

#pragma unroll
  for (int i = 0; i < 16; ++i) {
    int n = n0 + nbase + i;
    float rs = acc[i].x * as0 + acc[i].y * as1 + acc[i].z * as2 + acc[i].w * as3;
    float rd = acc[i].x * ad0 + acc[i].y * ad1 + acc[i].z * ad2 + acc[i].w * ad3;
#pragma unroll
    for (int m = 1; m < 16; m <<= 1) {   // reduce within 16-lane group (= one head)
      rs += __shfl_xor(rs, m, 64);
      rd += __shfl_xor(rd, m, 64);
    }
    if (n < N) {
      ushort4 hv;
      hv.x = f2bf(acc[i].x); hv.y = f2bf(acc[i].y);
      hv.z = f2bf(acc[i].z); hv.w = f2bf(acc[i].w);
      *(ushort4*)(&h[(long long)n * 256 + 4 * c]) = hv;   // 512B coalesced wave-store
      if ((c & 15) == 0) {
        a_s[(long long)n * 4 + hh] = rs;
        a_d[(long long)n * 4 + hh] = rd;
      }
    }
  }
}

// ---------------------------------------------------------------- time projection
__global__ void k_tp(const float* __restrict__ time_emb, const float* __restrict__ tp_w,
                     const float* __restrict__ tp_b, float* __restrict__ tp, int B) {
  int tid = blockIdx.x * blockDim.x + threadIdx.x;
  if (tid >= B * 64) return;
  int b = tid >> 6, c = tid & 63;
  const float* te = time_emb + (long long)b * 128;
  const float* wr = tp_w + (long long)c * 128;
  float s = 0.f;
  for (int k = 0; k < 128; ++k) {
    float t = te[k];
    s += (t / (1.f + __expf(-t))) * wr[k];
  }
  tp[tid] = s + tp_b[c];
}

// ---------------------------------------------------------------- CSR build: hist
__global__ __launch_bounds__(256) void k_hist(const int* __restrict__ dst32,
                                              int* __restrict__ cnt,
                                              long long E, long long N) {
  long long Etot = E + N;
  for (long long e = blockIdx.x * (long long)blockDim.x + threadIdx.x; e < Etot;
       e += (long long)gridDim.x * blockDim.x) {
    int dst = (e < E) ? dst32[e] : (int)(e - E);
    atomicAdd(cnt + dst, 1);
  }
}

// ---------------------------------------------------------------- CSR build: scan
__global__ __launch_bounds__(1024) void k_scan(const int* __restrict__ cnt,
                                               int* __restrict__ rowptr,
                                               int* __restrict__ cursor, int N, int SC) {
  __shared__ int wsum[16];
  __shared__ int carry_sm;
  int tid = threadIdx.x, lane = tid & 63, w = tid >> 6;
  if (tid == 0) carry_sm = 0;
  __syncthreads();
  int nchunk = SC / 4096;
  for (int c = 0; c < nchunk; ++c) {
    int base = c * 4096 + tid * 4;
    int4 v = *(const int4*)(cnt + base);
    int t0 = v.x, t1 = t0 + v.y, t2 = t1 + v.z, t3 = t2 + v.w;
    int s = t3;                                   // thread total
#pragma unroll
    for (int off = 1; off < 64; off <<= 1) {      // wave inclusive scan
      int t = __shfl_up(s, off, 64);
      if (lane >= off) s += t;
    }
    if (lane == 63) wsum[w] = s;
    __syncthreads();
    if (w == 0) {                                 // scan the 16 wave totals
      int t = (lane < 16) ? wsum[lane] : 0;
#pragma unroll
      for (int off = 1; off < 16; off <<= 1) {
        int u = __shfl_up(t, off, 64);
        if (lane >= off) t += u;
      }
      if (lane < 16) wsum[lane] = t;
    }
    __syncthreads();
    int woff = (w == 0) ? 0 : wsum[w - 1];
    int e0 = carry_sm + woff + (s - t3);          // exclusive prefix of v.x
    int4 ov = make_int4(e0, e0 + t0, e0 + t1, e0 + t2);
    *(int4*)(rowptr + base) = ov;
    *(int4*)(cursor + base) = ov;
    __syncthreads();
    if (tid == 0) carry_sm += wsum[15];
    __syncthreads();
  }
  if (tid == 0) rowptr[N] = carry_sm;
}

// ---------------------------------------------------------------- CSR build: scatter
__global__ __launch_bounds__(256) void k_scatter(const int* __restrict__ src32,
                                                 const int* __restrict__ dst32,
                                                 int* __restrict__ cursor,
                                                 int* __restrict__ col,
                                                 long long E, long long N) {
  long long Etot = E + N;
  for (long long e = blockIdx.x * (long long)blockDim.x + threadIdx.x; e < Etot;
       e += (long long)gridDim.x * blockDim.x) {
    int src, dst;
    if (e < E) { src = src32[e]; dst = dst32[e]; }
    else       { src = dst = (int)(e - E); }
    int pos = atomicAdd(cursor + dst, 1);
    col[pos] = src;
  }
}

// ---------------------------------------------------------------- fused aggregate + epilogue
// Grid-stride wave per dst node; 4-edge pipeline; bf16 h gather (halved bytes
// on the saturated L2-miss path). Accumulation order preserved.
__global__ __launch_bounds__(256) void k_agg_csr(const int* __restrict__ rowptr,
                                                 const int* __restrict__ col,
                                                 const float* __restrict__ a_s,
                                                 const float* __restrict__ a_d,
                                                 const unsigned short* __restrict__ h,
                                                 const float* __restrict__ conv_bias,
                                                 const float* __restrict__ tpo,
                                                 const void* __restrict__ batch,
                                                 const int* __restrict__ flag,
                                                 const float* __restrict__ ln_g,
                                                 const float* __restrict__ ln_b,
                                                 float* __restrict__ out, long long N) {
  int lane = threadIdx.x & 63;
  int is64 = *flag;
  long long wid = ((long long)blockIdx.x * blockDim.x + threadIdx.x) >> 6;
  long long nw  = ((long long)gridDim.x * blockDim.x) >> 6;
  float cb = conv_bias[lane];
  float gg = ln_g[lane], bb = ln_b[lane];
  const unsigned short* hl = h + lane;

  for (long long n = wid; n < N; n += nw) {
    float4 ad4 = *(const float4*)(a_d + n * 4);
    int beg = rowptr[n], end = rowptr[n + 1];   // end > beg (self-loop)
    float d0 = 0.f, d1 = 0.f, d2 = 0.f, d3 = 0.f;
    float n0 = 0.f, n1 = 0.f, n2 = 0.f, n3 = 0.f;
    int e = beg;
    for (; e + 3 < end; e += 4) {               // 4-edge pipelined body
      int s0 = col[e], s1 = col[e + 1], s2 = col[e + 2], s3 = col[e + 3];
      float4 A0 = *(const float4*)(a_s + (long long)s0 * 4);
      float4 A1 = *(const float4*)(a_s + (long long)s1 * 4);
      float4 A2 = *(const float4*)(a_s + (long long)s2 * 4);
      float4 A3 = *(const float4*)(a_s + (long long)s3 * 4);
      const unsigned short* p0 = hl + (long long)s0 * 256;
      const unsigned short* p1 = hl + (long long)s1 * 256;
      const unsigned short* p2 = hl + (long long)s2 * 256;
      const unsigned short* p3 = hl + (long long)s3 * 256;
      unsigned short b00 = p0[0], b01 = p0[64], b02 = p0[128], b03 = p0[192];
      unsigned short b10 = p1[0], b11 = p1[64], b12 = p1[128], b13 = p1[192];
      unsigned short b20 = p2[0], b21 = p2[64], b22 = p2[128], b23 = p2[192];
      unsigned short b30 = p3[0], b31 = p3[64], b32 = p3[128], b33 = p3[192];

      float l0, l1, l2, l3, x0, x1, x2, x3;
      l0 = A0.x + ad4.x; l1 = A0.y + ad4.y; l2 = A0.z + ad4.z; l3 = A0.w + ad4.w;
      l0 = fmaxf(l0, NEG_SLOPE * l0); l1 = fmaxf(l1, NEG_SLOPE * l1);
      l2 = fmaxf(l2, NEG_SLOPE * l2); l3 = fmaxf(l3, NEG_SLOPE * l3);
      x0 = __expf(l0); x1 = __expf(l1); x2 = __expf(l2); x3 = __expf(l3);
      d0 += x0; d1 += x1; d2 += x2; d3 += x3;
      n0 = fmaf(x0, BF2F(b00), n0); n1 = fmaf(x1, BF2F(b01), n1);
      n2 = fmaf(x2, BF2F(b02), n2); n3 = fmaf(x3, BF2F(b03), n3);

      l0 = A1.x + ad4.x; l1 = A1.y + ad4.y; l2 = A1.z + ad4.z; l3 = A1.w + ad4.w;
      l0 = fmaxf(l0, NEG_SLOPE * l0); l1 = fmaxf(l1, NEG_SLOPE * l1);
      l2 = fmaxf(l2, NEG_SLOPE * l2); l3 = fmaxf(l3, NEG_SLOPE * l3);
      x0 = __expf(l0); x1 = __expf(l1); x2 = __expf(l2); x3 = __expf(l3);
      d0 += x0; d1 += x1; d2 += x2; d3 += x3;
      n0 = fmaf(x0, BF2F(b10), n0); n1 = fmaf(x1, BF2F(b11), n1);
      n2 = fmaf(x2, BF2F(b12), n2); n3 = fmaf(x3, BF2F(b13), n3);

      l0 = A2.x + ad4.x; l1 = A2.y + ad4.y; l2 = A2.z + ad4.z; l3 = A2.w + ad4.w;
      l0 = fmaxf(l0, NEG_SLOPE * l0); l1 = fmaxf(l1, NEG_SLOPE * l1);
      l2 = fmaxf(l2, NEG_SLOPE * l2); l3 = fmaxf(l3, NEG_SLOPE * l3);
      x0 = __expf(l0); x1 = __expf(l1); x2 = __expf(l2); x3 = __expf(l3);
      d0 += x0; d1 += x1; d2 += x2; d3 += x3;
      n0 = fmaf(x0, BF2F(b20), n0); n1 = fmaf(x1, BF2F(b21), n1);
      n2 = fmaf(x2, BF2F(b22), n2); n3 = fmaf(x3, BF2F(b23), n3);

      l0 = A3.x + ad4.x; l1 = A3.y + ad4.y; l2 = A3.z + ad4.z; l3 = A3.w + ad4.w;
      l0 = fmaxf(l0, NEG_SLOPE * l0); l1 = fmaxf(l1, NEG_SLOPE * l1);
      l2 = fmaxf(l2, NEG_SLOPE * l2); l3 = fmaxf(l3, NEG_SLOPE * l3);
      x0 = __expf(l0); x1 = __expf(l1); x2 = __expf(l2); x3 = __expf(l3);
      d0 += x0; d1 += x1; d2 += x2; d3 += x3;
      n0 = fmaf(x0, BF2F(b30), n0); n1 = fmaf(x1, BF2F(b31), n1);
      n2 = fmaf(x2, BF2F(b32), n2); n3 = fmaf(x3, BF2F(b33), n3);
    }
    for (; e < end; ++e) {                      // tail (<=3 edges)
      int src = col[e];
      float4 as4 = *(const float4*)(a_s + (long long)src * 4);
      const unsigned short* hp = hl + (long long)src * 256;
      unsigned short c0 = hp[0], c1 = hp[64], c2 = hp[128], c3 = hp[192];
      float l0 = as4.x + ad4.x; l0 = fmaxf(l0, NEG_SLOPE * l0);
      float l1 = as4.y + ad4.y; l1 = fmaxf(l1, NEG_SLOPE * l1);
      float l2 = as4.z + ad4.z; l2 = fmaxf(l2, NEG_SLOPE * l2);
      float l3 = as4.w + ad4.w; l3 = fmaxf(l3, NEG_SLOPE * l3);
      float s0 = __expf(l0), s1 = __expf(l1), s2 = __expf(l2), s3 = __expf(l3);
      d0 += s0; d1 += s1; d2 += s2; d3 += s3;
      n0 = fmaf(s0, BF2F(c0), n0); n1 = fmaf(s1, BF2F(c1), n1);
      n2 = fmaf(s2, BF2F(c2), n2); n3 = fmaf(s3, BF2F(c3), n3);
    }
    float v = 0.25f * (n0 / (d0 + 1e-16f) + n1 / (d1 + 1e-16f) +
                       n2 / (d2 + 1e-16f) + n3 / (d3 + 1e-16f));
    long long b = load_idx(batch, n, is64);
    v += cb + tpo[b * 64 + lane];
    float t1 = v, t2 = v * v;
#pragma unroll
    for (int m = 32; m; m >>= 1) {
      t1 += __shfl_xor(t1, m, 64);
      t2 += __shfl_xor(t2, m, 64);
    }
    float mean = t1 * (1.f / 64.f);
    float var  = t2 * (1.f / 64.f) - mean * mean;
    float y = (v - mean) * rsqrtf(var + LN_EPS) * gg + bb;
    out[n * 64 + lane] = y / (1.f + __expf(-y));
  }
}

// ----------------------------------------------------------------------------
extern "C" void kernel_launch(void* const* d_in, const int* in_sizes, int n_in,
                              void* d_out, int out_size, void* d_ws, size_t ws_size,
                              hipStream_t stream) {
  const float* x        = (const float*)d_in[0];
  const void*  ei       = d_in[1];
  const float* time_emb = (const float*)d_in[2];
  const void*  batch    = d_in[3];
  const float* W        = (const float*)d_in[4];
  const float* att_src  = (const float*)d_in[5];
  const float* att_dst  = (const float*)d_in[6];
  const float* conv_b   = (const float*)d_in[7];
  const float* tp_w     = (const float*)d_in[8];
  const float* tp_b     = (const float*)d_in[9];
  const float* ln_g     = (const float*)d_in[10];
  const float* ln_b     = (const float*)d_in[11];

  long long N = in_sizes[0] / 128;   // 50000
  long long E = in_sizes[1] / 2;     // 800000
  long long B = in_sizes[2] / 128;   // 16
  long long Etot = E + N;
  long long SC = ((N + 4095) / 4096) * 4096;   // scan-padded length

  // workspace layout (256B-aligned chunks), ~45 MB total
  char* p = (char*)d_ws;
  int*   flag   = (int*)p;   p += 256;
  unsigned short* h = (unsigned short*)p; p += (size_t)N * 256 * 2;  // 25.6 MB bf16
  float* WT     = (float*)p; p += (size_t)128 * 256 * 4;   // 131 KB
  float* a_s    = (float*)p; p += (size_t)N * 4 * 4;       // 800 KB
  float* a_d    = (float*)p; p += (size_t)N * 4 * 4;       // 800 KB
  int*   src32  = (int*)p;   p += (size_t)E * 4;           // 3.2 MB
  int*   dst32  = (int*)p;   p += (size_t)E * 4;           // 3.2 MB
  int*   cnt    = (int*)p;   p += (size_t)SC * 4;          // padded
  int*   rowptr = (int*)p;   p += (size_t)(SC + 64) * 4;   // padded
  int*   cursor = (int*)p;   p += (size_t)SC * 4;          // padded
  int*   col    = (int*)p;   p += (size_t)Etot * 4;        // 3.4 MB
  float* tpo    = (float*)p; p += (size_t)B * 64 * 4;      // 4 KB

  hipMemsetAsync(cnt, 0, (size_t)SC * 4, stream);

  k_detect<<<dim3(1), 64, 0, stream>>>(ei, E, N, flag);
  k_cvt<<<dim3((unsigned)((E + 255) / 256)), 256, 0, stream>>>(ei, flag, src32, dst32, E);
  k_wt<<<dim3(128), 256, 0, stream>>>(W, WT);
  k_gemm<<<dim3((unsigned)((N + 63) / 64)), 256, 0, stream>>>(x, WT, att_src, att_dst,
                                                              h, a_s, a_d, (int)N);
  k_tp<<<dim3((unsigned)((B * 64 + 255) / 256)), 256, 0, stream>>>(time_emb, tp_w, tp_b, tpo, (int)B);
  k_hist<<<dim3(2048), 256, 0, stream>>>(dst32, cnt, E, N);
  k_scan<<<dim3(1), 1024, 0, stream>>>(cnt, rowptr, cursor, (int)N, (int)SC);
  k_scatter<<<dim3(2048), 256, 0, stream>>>(src32, dst32, cursor, col, E, N);
  k_agg_csr<<<dim3(2048), 256, 0, stream>>>(rowptr, col, a_s, a_d, h, conv_b, tpo,
                                            batch, flag, ln_g, ln_b, (float*)d_out, N);
}

// Round 11
// 341.447 us; speedup vs baseline: 1.4436x; 1.0921x over previous
//
#include <hip/hip_runtime.h>
#include <math.h>

// GraphDiffusionBlock: GAT(4 heads x 64ch) + time-proj + LayerNorm + SiLU
// Pipeline: detect idx dtype -> cvt edges int32 -> W transpose ->
//           GEMM h=xWT (32-node tiles for occupancy; f32 logits, bf16 h) ->
//           time proj -> hist/scan -> scatter (+per-edge exp into CSR order) ->
//           fused aggregate+epilogue (no exp, broadcast s4 + bf16 h gather).
// R10 evidence: agg VALUBusy 59% = wave-uniform exp duplicated 64x -> move to
// scatter (thread-per-edge). gemm ~100us at 17.7% occupancy -> smaller tiles.

#define LN_EPS 1e-5f
#define NEG_SLOPE 0.2f

__device__ __forceinline__ unsigned short f2bf(float f) {   // RNE bf16
  unsigned int u = __float_as_uint(f);
  u += 0x7FFFu + ((u >> 16) & 1u);
  return (unsigned short)(u >> 16);
}
#define BF2F(v) __uint_as_float(((unsigned)(v)) << 16)

// ---------------------------------------------------------------- dtype detect
__global__ void k_detect(const void* __restrict__ idx, long long n64, long long maxval,
                         int* __restrict__ flag) {
  int lane = threadIdx.x;
  long long cnt = n64 < 64 ? n64 : 64;
  int bad = 0;
  if (lane < cnt) {
    long long v = ((const long long*)idx)[lane];
    bad = (v < 0 || v >= maxval) ? 1 : 0;
  }
  unsigned long long m = __ballot(bad);
  if (lane == 0) *flag = (m == 0ULL) ? 1 : 0;
}

__device__ __forceinline__ long long load_idx(const void* p, long long i, int is64) {
  return is64 ? ((const long long*)p)[i] : (long long)((const int*)p)[i];
}

// ---------------------------------------------------------------- edge cvt -> int32
__global__ __launch_bounds__(256) void k_cvt(const void* __restrict__ ei,
                                             const int* __restrict__ flag,
                                             int* __restrict__ src32,
                                             int* __restrict__ dst32, long long E) {
  long long i = (long long)blockIdx.x * blockDim.x + threadIdx.x;
  if (i >= E) return;
  int is64 = *flag;
  src32[i] = (int)load_idx(ei, i, is64);
  dst32[i] = (int)load_idx(ei, E + i, is64);
}

// ---------------------------------------------------------------- W transpose
__global__ __launch_bounds__(256) void k_wt(const float* __restrict__ W,
                                            float* __restrict__ WT) {
  int i = blockIdx.x * 256 + threadIdx.x;   // 32768 elements
  int c = i >> 7, k = i & 127;
  WT[k * 256 + c] = W[i];
}

// ---------------------------------------------------------------- GEMM h = x @ W^T  (+ att logits)
// 32-node tile (16KB LDS) -> 1563 blocks = 6.1/CU (was 781 = 3/CU, occ 17.7%).
// Thread (w=tid>>6 -> nodes w*8..w*8+7, c=tid&63 -> channels 4c..4c+3).
// Per 4-k: 4 coalesced WT float4 loads + 8 LDS broadcasts + 128 FMAs.
__global__ __launch_bounds__(256) void k_gemm(const float* __restrict__ x,
                                              const float* __restrict__ WT,
                                              const float* __restrict__ att_src,
                                              const float* __restrict__ att_dst,
                                              unsigned short* __restrict__ h,
                                              float* __restrict__ a_s,
                                              float* __restrict__ a_d, int N) {
  __shared__ float xs[32][128];
  int n0 = blockIdx.x * 32;
  int tid = threadIdx.x;
  for (int i = tid; i < 32 * 32; i += 256) {   // stage x tile (1024 float4)
    int n = i >> 5;
    int k4 = i & 31;
    float4 v = make_float4(0.f, 0.f, 0.f, 0.f);
    if (n0 + n < N) v = reinterpret_cast<const float4*>(x)[(long long)(n0 + n) * 32 + k4];
    reinterpret_cast<float4*>(&xs[n][0])[k4] = v;
  }
  __syncthreads();

  int c = tid & 63;          // channel-quad id: global channels 4c..4c+3
  int w = tid >> 6;          // wave -> nodes [w*8, w*8+8)
  int nbase = w * 8;
  const float4* wt4 = reinterpret_cast<const float4*>(WT) + c;   // row k: wt4[k*64]

  float4 acc[8];
#pragma unroll
  for (int i = 0; i < 8; ++i) acc[i] = make_float4(0.f, 0.f, 0.f, 0.f);

  for (int k = 0; k < 128; k += 4) {
    float4 w0 = wt4[(k + 0) * 64];
    float4 w1 = wt4[(k + 1) * 64];
    float4 w2 = wt4[(k + 2) * 64];
    float4 w3 = wt4[(k + 3) * 64];
#pragma unroll
    for (int i = 0; i < 8; ++i) {
      float4 xv = *(const float4*)(&xs[nbase + i][k]);
      acc[i].x += xv.x * w0.x + xv.y * w1.x + xv.z * w2.x + xv.w * w3.x;
      acc[i].y += xv.x * w0.y + xv.y * w1.y + xv.z * w2.y + xv.w * w3.y;
      acc[i].z += xv.x * w0.z + xv.y * w1.z + xv.z * w2.z + xv.w * w3.z;
      acc[i].w += xv.x * w0.w + xv.y * w1.w + xv.z * w2.w + xv.w * w3.w;
    }
  }

  int hh = c >> 4;
  int cb = 4 * (c & 15);
  float as0 = att_src[hh * 64 + cb + 0], as1 = att_src[hh * 64 + cb + 1];
  float as2 = att_src[hh * 64 + cb + 2], as3 = att_src[hh * 64 + cb + 3];
  float ad0 = att_dst[hh * 64 + cb + 0], ad1 = att_dst[hh * 64 + cb + 1];
  float ad2 = att_dst[hh * 64 + cb + 2], ad3 = att_dst[hh * 64 + cb + 3];

#pragma unroll
  for (int i = 0; i < 8; ++i) {
    int n = n0 + nbase + i;
    float rs = acc[i].x * as0 + acc[i].y * as1 + acc[i].z * as2 + acc[i].w * as3;
    float rd = acc[i].x * ad0 + acc[i].y * ad1 + acc[i].z * ad2 + acc[i].w * ad3;
#pragma unroll
    for (int m = 1; m < 16; m <<= 1) {   // reduce within 16-lane group (= one head)
      rs += __shfl_xor(rs, m, 64);
      rd += __shfl_xor(rd, m, 64);
    }
    if (n < N) {
      ushort4 hv;
      hv.x = f2bf(acc[i].x); hv.y = f2bf(acc[i].y);
      hv.z = f2bf(acc[i].z); hv.w = f2bf(acc[i].w);
      *(ushort4*)(&h[(long long)n * 256 + 4 * c]) = hv;   // 512B coalesced wave-store
      if ((c & 15) == 0) {
        a_s[(long long)n * 4 + hh] = rs;
        a_d[(long long)n * 4 + hh] = rd;
      }
    }
  }
}

// ---------------------------------------------------------------- time projection
__global__ void k_tp(const float* __restrict__ time_emb, const float* __restrict__ tp_w,
                     const float* __restrict__ tp_b, float* __restrict__ tp, int B) {
  int tid = blockIdx.x * blockDim.x + threadIdx.x;
  if (tid >= B * 64) return;
  int b = tid >> 6, c = tid & 63;
  const float* te = time_emb + (long long)b * 128;
  const float* wr = tp_w + (long long)c * 128;
  float s = 0.f;
  for (int k = 0; k < 128; ++k) {
    float t = te[k];
    s += (t / (1.f + __expf(-t))) * wr[k];
  }
  tp[tid] = s + tp_b[c];
}

// ---------------------------------------------------------------- CSR build: hist
__global__ __launch_bounds__(256) void k_hist(const int* __restrict__ dst32,
                                              int* __restrict__ cnt,
                                              long long E, long long N) {
  long long Etot = E + N;
  for (long long e = blockIdx.x * (long long)blockDim.x + threadIdx.x; e < Etot;
       e += (long long)gridDim.x * blockDim.x) {
    int dst = (e < E) ? dst32[e] : (int)(e - E);
    atomicAdd(cnt + dst, 1);
  }
}

// ---------------------------------------------------------------- CSR build: scan
__global__ __launch_bounds__(1024) void k_scan(const int* __restrict__ cnt,
                                               int* __restrict__ rowptr,
                                               int* __restrict__ cursor, int N, int SC) {
  __shared__ int wsum[16];
  __shared__ int carry_sm;
  int tid = threadIdx.x, lane = tid & 63, w = tid >> 6;
  if (tid == 0) carry_sm = 0;
  __syncthreads();
  int nchunk = SC / 4096;
  for (int c = 0; c < nchunk; ++c) {
    int base = c * 4096 + tid * 4;
    int4 v = *(const int4*)(cnt + base);
    int t0 = v.x, t1 = t0 + v.y, t2 = t1 + v.z, t3 = t2 + v.w;
    int s = t3;                                   // thread total
#pragma unroll
    for (int off = 1; off < 64; off <<= 1) {      // wave inclusive scan
      int t = __shfl_up(s, off, 64);
      if (lane >= off) s += t;
    }
    if (lane == 63) wsum[w] = s;
    __syncthreads();
    if (w == 0) {                                 // scan the 16 wave totals
      int t = (lane < 16) ? wsum[lane] : 0;
#pragma unroll
      for (int off = 1; off < 16; off <<= 1) {
        int u = __shfl_up(t, off, 64);
        if (lane >= off) t += u;
      }
      if (lane < 16) wsum[lane] = t;
    }
    __syncthreads();
    int woff = (w == 0) ? 0 : wsum[w - 1];
    int e0 = carry_sm + woff + (s - t3);          // exclusive prefix of v.x
    int4 ov = make_int4(e0, e0 + t0, e0 + t1, e0 + t2);
    *(int4*)(rowptr + base) = ov;
    *(int4*)(cursor + base) = ov;
    __syncthreads();
    if (tid == 0) carry_sm += wsum[15];
    __syncthreads();
  }
  if (tid == 0) rowptr[N] = carry_sm;
}

// ---------------------------------------------------------------- CSR build: scatter (+edge exp)
// Computes the per-edge softmax numerators here (thread-per-edge: no 64x wave
// duplication) and stores them in CSR order: s4[pos]. Same inputs, same ops,
// same __expf as before -> bit-identical to computing in agg.
__global__ __launch_bounds__(256) void k_scatter(const int* __restrict__ src32,
                                                 const int* __restrict__ dst32,
                                                 const float* __restrict__ a_s,
                                                 const float* __restrict__ a_d,
                                                 int* __restrict__ cursor,
                                                 int* __restrict__ col,
                                                 float* __restrict__ s4,
                                                 long long E, long long N) {
  long long Etot = E + N;
  for (long long e = blockIdx.x * (long long)blockDim.x + threadIdx.x; e < Etot;
       e += (long long)gridDim.x * blockDim.x) {
    int src, dst;
    if (e < E) { src = src32[e]; dst = dst32[e]; }
    else       { src = dst = (int)(e - E); }
    int pos = atomicAdd(cursor + dst, 1);
    col[pos] = src;
    float4 A = *(const float4*)(a_s + (long long)src * 4);
    float4 D = *(const float4*)(a_d + (long long)dst * 4);
    float l0 = A.x + D.x; l0 = fmaxf(l0, NEG_SLOPE * l0);
    float l1 = A.y + D.y; l1 = fmaxf(l1, NEG_SLOPE * l1);
    float l2 = A.z + D.z; l2 = fmaxf(l2, NEG_SLOPE * l2);
    float l3 = A.w + D.w; l3 = fmaxf(l3, NEG_SLOPE * l3);
    float4 sv = make_float4(__expf(l0), __expf(l1), __expf(l2), __expf(l3));
    *(float4*)(s4 + (long long)pos * 4) = sv;
  }
}

// ---------------------------------------------------------------- fused aggregate + epilogue
// Grid-stride wave per dst node; per edge: broadcast s4 (16B) + 4 bf16 h
// gathers + 4 add + 4 fma + BF2F. No exp, no leaky (moved to scatter).
__global__ __launch_bounds__(256) void k_agg_csr(const int* __restrict__ rowptr,
                                                 const int* __restrict__ col,
                                                 const float* __restrict__ s4,
                                                 const unsigned short* __restrict__ h,
                                                 const float* __restrict__ conv_bias,
                                                 const float* __restrict__ tpo,
                                                 const void* __restrict__ batch,
                                                 const int* __restrict__ flag,
                                                 const float* __restrict__ ln_g,
                                                 const float* __restrict__ ln_b,
                                                 float* __restrict__ out, long long N) {
  int lane = threadIdx.x & 63;
  int is64 = *flag;
  long long wid = ((long long)blockIdx.x * blockDim.x + threadIdx.x) >> 6;
  long long nw  = ((long long)gridDim.x * blockDim.x) >> 6;
  float cb = conv_bias[lane];
  float gg = ln_g[lane], bb = ln_b[lane];
  const unsigned short* hl = h + lane;

  for (long long n = wid; n < N; n += nw) {
    int beg = rowptr[n], end = rowptr[n + 1];   // end > beg (self-loop)
    float d0 = 0.f, d1 = 0.f, d2 = 0.f, d3 = 0.f;
    float n0 = 0.f, n1 = 0.f, n2 = 0.f, n3 = 0.f;
    int e = beg;
    for (; e + 3 < end; e += 4) {               // 4-edge pipelined body
      int c0 = col[e], c1 = col[e + 1], c2 = col[e + 2], c3 = col[e + 3];
      float4 S0 = *(const float4*)(s4 + (long long)(e + 0) * 4);
      float4 S1 = *(const float4*)(s4 + (long long)(e + 1) * 4);
      float4 S2 = *(const float4*)(s4 + (long long)(e + 2) * 4);
      float4 S3 = *(const float4*)(s4 + (long long)(e + 3) * 4);
      const unsigned short* p0 = hl + (long long)c0 * 256;
      const unsigned short* p1 = hl + (long long)c1 * 256;
      const unsigned short* p2 = hl + (long long)c2 * 256;
      const unsigned short* p3 = hl + (long long)c3 * 256;
      unsigned short b00 = p0[0], b01 = p0[64], b02 = p0[128], b03 = p0[192];
      unsigned short b10 = p1[0], b11 = p1[64], b12 = p1[128], b13 = p1[192];
      unsigned short b20 = p2[0], b21 = p2[64], b22 = p2[128], b23 = p2[192];
      unsigned short b30 = p3[0], b31 = p3[64], b32 = p3[128], b33 = p3[192];

      d0 += S0.x; d1 += S0.y; d2 += S0.z; d3 += S0.w;
      n0 = fmaf(S0.x, BF2F(b00), n0); n1 = fmaf(S0.y, BF2F(b01), n1);
      n2 = fmaf(S0.z, BF2F(b02), n2); n3 = fmaf(S0.w, BF2F(b03), n3);

      d0 += S1.x; d1 += S1.y; d2 += S1.z; d3 += S1.w;
      n0 = fmaf(S1.x, BF2F(b10), n0); n1 = fmaf(S1.y, BF2F(b11), n1);
      n2 = fmaf(S1.z, BF2F(b12), n2); n3 = fmaf(S1.w, BF2F(b13), n3);

      d0 += S2.x; d1 += S2.y; d2 += S2.z; d3 += S2.w;
      n0 = fmaf(S2.x, BF2F(b20), n0); n1 = fmaf(S2.y, BF2F(b21), n1);
      n2 = fmaf(S2.z, BF2F(b22), n2); n3 = fmaf(S2.w, BF2F(b23), n3);

      d0 += S3.x; d1 += S3.y; d2 += S3.z; d3 += S3.w;
      n0 = fmaf(S3.x, BF2F(b30), n0); n1 = fmaf(S3.y, BF2F(b31), n1);
      n2 = fmaf(S3.z, BF2F(b32), n2); n3 = fmaf(S3.w, BF2F(b33), n3);
    }
    for (; e < end; ++e) {                      // tail (<=3 edges)
      int src = col[e];
      float4 S = *(const float4*)(s4 + (long long)e * 4);
      const unsigned short* hp = hl + (long long)src * 256;
      unsigned short u0 = hp[0], u1 = hp[64], u2 = hp[128], u3 = hp[192];
      d0 += S.x; d1 += S.y; d2 += S.z; d3 += S.w;
      n0 = fmaf(S.x, BF2F(u0), n0); n1 = fmaf(S.y, BF2F(u1), n1);
      n2 = fmaf(S.z, BF2F(u2), n2); n3 = fmaf(S.w, BF2F(u3), n3);
    }
    float v = 0.25f * (n0 / (d0 + 1e-16f) + n1 / (d1 + 1e-16f) +
                       n2 / (d2 + 1e-16f) + n3 / (d3 + 1e-16f));
    long long b = load_idx(batch, n, is64);
    v += cb + tpo[b * 64 + lane];
    float t1 = v, t2 = v * v;
#pragma unroll
    for (int m = 32; m; m >>= 1) {
      t1 += __shfl_xor(t1, m, 64);
      t2 += __shfl_xor(t2, m, 64);
    }
    float mean = t1 * (1.f / 64.f);
    float var  = t2 * (1.f / 64.f) - mean * mean;
    float y = (v - mean) * rsqrtf(var + LN_EPS) * gg + bb;
    out[n * 64 + lane] = y / (1.f + __expf(-y));
  }
}

// ----------------------------------------------------------------------------
extern "C" void kernel_launch(void* const* d_in, const int* in_sizes, int n_in,
                              void* d_out, int out_size, void* d_ws, size_t ws_size,
                              hipStream_t stream) {
  const float* x        = (const float*)d_in[0];
  const void*  ei       = d_in[1];
  const float* time_emb = (const float*)d_in[2];
  const void*  batch    = d_in[3];
  const float* W        = (const float*)d_in[4];
  const float* att_src  = (const float*)d_in[5];
  const float* att_dst  = (const float*)d_in[6];
  const float* conv_b   = (const float*)d_in[7];
  const float* tp_w     = (const float*)d_in[8];
  const float* tp_b     = (const float*)d_in[9];
  const float* ln_g     = (const float*)d_in[10];
  const float* ln_b     = (const float*)d_in[11];

  long long N = in_sizes[0] / 128;   // 50000
  long long E = in_sizes[1] / 2;     // 800000
  long long B = in_sizes[2] / 128;   // 16
  long long Etot = E + N;
  long long SC = ((N + 4095) / 4096) * 4096;   // scan-padded length

  // workspace layout (256B-aligned chunks), ~52 MB total
  char* p = (char*)d_ws;
  int*   flag   = (int*)p;   p += 256;
  unsigned short* h = (unsigned short*)p; p += (size_t)N * 256 * 2;  // 25.6 MB bf16
  float* WT     = (float*)p; p += (size_t)128 * 256 * 4;   // 131 KB
  float* a_s    = (float*)p; p += (size_t)N * 4 * 4;       // 800 KB
  float* a_d    = (float*)p; p += (size_t)N * 4 * 4;       // 800 KB
  int*   src32  = (int*)p;   p += (size_t)E * 4;           // 3.2 MB
  int*   dst32  = (int*)p;   p += (size_t)E * 4;           // 3.2 MB
  int*   cnt    = (int*)p;   p += (size_t)SC * 4;          // padded
  int*   rowptr = (int*)p;   p += (size_t)(SC + 64) * 4;   // padded
  int*   cursor = (int*)p;   p += (size_t)SC * 4;          // padded
  int*   col    = (int*)p;   p += (size_t)Etot * 4;        // 3.4 MB
  float* s4     = (float*)p; p += (size_t)Etot * 4 * 4;    // 13.6 MB
  float* tpo    = (float*)p; p += (size_t)B * 64 * 4;      // 4 KB

  hipMemsetAsync(cnt, 0, (size_t)SC * 4, stream);

  k_detect<<<dim3(1), 64, 0, stream>>>(ei, E, N, flag);
  k_cvt<<<dim3((unsigned)((E + 255) / 256)), 256, 0, stream>>>(ei, flag, src32, dst32, E);
  k_wt<<<dim3(128), 256, 0, stream>>>(W, WT);
  k_gemm<<<dim3((unsigned)((N + 31) / 32)), 256, 0, stream>>>(x, WT, att_src, att_dst,
                                                              h, a_s, a_d, (int)N);
  k_tp<<<dim3((unsigned)((B * 64 + 255) / 256)), 256, 0, stream>>>(time_emb, tp_w, tp_b, tpo, (int)B);
  k_hist<<<dim3(2048), 256, 0, stream>>>(dst32, cnt, E, N);
  k_scan<<<dim3(1), 1024, 0, stream>>>(cnt, rowptr, cursor, (int)N, (int)SC);
  k_scatter<<<dim3(2048), 256, 0, stream>>>(src32, dst32, a_s, a_d, cursor, col, s4, E, N);
  k_agg_csr<<<dim3(2048), 256, 0, stream>>>(rowptr, col, s4, h, conv_b, tpo,
                                            batch, flag, ln_g, ln_b, (float*)d_out, N);
}